// Round 4
// baseline (731.666 us; speedup 1.0000x reference)
//
#include <hip/hip_runtime.h>
#include <hip/hip_bf16.h>

#define N_NODES 12000
#define N_EDGES 384000
#define F_IN 512
#define H 64
#define C_CLS 7
#define KTERMS 16
#define PAD 96
#define NBLK 768
#define NT 256
#define GEMM_BLKS 384
#define NGROUP (N_NODES / 4)
#define MOM_BLKS 192

__device__ __forceinline__ float wred_f(float x) {
    #pragma unroll
    for (int o = 32; o > 0; o >>= 1) x += __shfl_xor(x, o);
    return x;
}

// grid-wide barrier: release/acquire agent-scope atomics (cross-XCD safe).
// bar is zeroed by the memset each call, so targets are call-local.
__device__ __forceinline__ void grid_sync(int* bar, int target) {
    __syncthreads();
    if (threadIdx.x == 0) {
        __hip_atomic_fetch_add(bar, 1, __ATOMIC_ACQ_REL, __HIP_MEMORY_SCOPE_AGENT);
        while (__hip_atomic_load(bar, __ATOMIC_ACQUIRE, __HIP_MEMORY_SCOPE_AGENT) < target)
            __builtin_amdgcn_s_sleep(1);
    }
    __syncthreads();
}

__global__ __launch_bounds__(NT, 4) void fused_k(
        const float* __restrict__ x, const float* __restrict__ W1,
        const float* __restrict__ b1, const float* __restrict__ W2,
        const float* __restrict__ b2, const float* __restrict__ aux,
        const float* __restrict__ clfW, const float* __restrict__ clfb,
        const int* __restrict__ ei,
        float* __restrict__ hbuf, float* __restrict__ h1, float* __restrict__ h2,
        float* __restrict__ score, int* __restrict__ csrc, int* __restrict__ cur,
        double* __restrict__ M, double* __restrict__ m0, int* __restrict__ bar,
        float* __restrict__ out) {
    // LDS union: gemm {xsT[64][34]@0, wsm[64][64]@8704} = 25088
    //            aggD {w2s[64][64]@0, anorm[64]@16384, gsh[4][64]@16640}
    //            momE {Msh[4][16][64]@0, Dsh[4][16]@16384, cw@17664, cb@21248}
    //            finF {Ms[16][64]@0, m0s@4096, zh[4][128]@4160, cw@17664, cb@21248}
    __shared__ __align__(16) char smem[25600];
    const int b = blockIdx.x, t = threadIdx.x;
    const int f = t & 63, w = t >> 6;

    // ============ phase A: gemm1 (blocks 0..383)  ||  padded-CSR fill ============
    if (b < GEMM_BLKS) {
        if (b * 32 < N_NODES) {
            float* xsT = (float*)smem;            // [64][34]
            float* wsm = (float*)(smem + 8704);   // [64][64]
            const int tx = t & 15, ty = t >> 4;
            const int i0 = b * 32;
            float acc[2][4] = {};
            for (int k0 = 0; k0 < F_IN; k0 += 64) {
                for (int idx = t; idx < 512; idx += NT) {
                    int m = idx >> 4, c4 = idx & 15;
                    float4 v = *(const float4*)(x + (size_t)(i0 + m) * F_IN + k0 + c4 * 4);
                    xsT[(c4 * 4 + 0) * 34 + m] = v.x;
                    xsT[(c4 * 4 + 1) * 34 + m] = v.y;
                    xsT[(c4 * 4 + 2) * 34 + m] = v.z;
                    xsT[(c4 * 4 + 3) * 34 + m] = v.w;
                }
                for (int idx = t; idx < 1024; idx += NT) {
                    int r = idx >> 4, c4 = idx & 15;
                    *(float4*)(&wsm[r * 64 + c4 * 4]) =
                        *(const float4*)(W1 + (size_t)(k0 + r) * H + c4 * 4);
                }
                __syncthreads();
                #pragma unroll
                for (int kk = 0; kk < 64; ++kk) {
                    float2 a = *(const float2*)(&xsT[kk * 34 + ty * 2]);
                    float4 bb = *(const float4*)(&wsm[kk * 64 + tx * 4]);
                    acc[0][0] += a.x * bb.x; acc[0][1] += a.x * bb.y;
                    acc[0][2] += a.x * bb.z; acc[0][3] += a.x * bb.w;
                    acc[1][0] += a.y * bb.x; acc[1][1] += a.y * bb.y;
                    acc[1][2] += a.y * bb.z; acc[1][3] += a.y * bb.w;
                }
                __syncthreads();
            }
            #pragma unroll
            for (int q = 0; q < 2; ++q) {
                float4 v = make_float4(acc[q][0], acc[q][1], acc[q][2], acc[q][3]);
                *(float4*)(hbuf + (size_t)(i0 + ty * 2 + q) * H + tx * 4) = v;
            }
        }
    } else {
        for (int e = (b - GEMM_BLKS) * NT + t; e < N_EDGES; e += (NBLK - GEMM_BLKS) * NT) {
            int s = ei[e];
            int d = ei[N_EDGES + e];
            int pos = atomicAdd(&cur[d], 1);
            if (pos < PAD) csrc[d * PAD + pos] = s;   // overflow guard (P ~ 1e-14)
        }
    }
    grid_sync(bar, NBLK);

    // ============ phase C: stage W2 + aux-norm; agg1 (Â·hbuf + b1, ReLU) ============
    float* w2s   = (float*)smem;             // [64][64]
    float* anorm = (float*)(smem + 16384);   // [64]
    float* gsh   = (float*)(smem + 16640);   // [4][64]
    #pragma unroll
    for (int q = 0; q < 4; ++q) {
        int idx = t + q * NT;
        int r = idx >> 4, c4 = idx & 15;
        *(float4*)(&w2s[r * 64 + c4 * 4]) = *(const float4*)(W2 + r * H + c4 * 4);
    }
    if (t < 64) {
        float av = aux[t];
        float an2 = wred_f(av * av);
        anorm[t] = av * rsqrtf(fmaxf(an2, 1e-24f));
    }
    for (int q = 0; q < 4; ++q) {
        int g = b + NBLK * q;
        if (g < NGROUP) {
            int i = g * 4 + w;
            int di = cur[i];
            float isd = rsqrtf((float)di + 1.f);
            float acc = hbuf[i * H + f] * (isd * isd) + b1[f];
            int deg = min(di, PAD);
            const int* rowp = csrc + i * PAD;
            int p = 0;
            for (; p + 4 <= deg; p += 4) {
                int s0 = rowp[p], s1 = rowp[p + 1], s2 = rowp[p + 2], s3 = rowp[p + 3];
                float w0 = rsqrtf((float)cur[s0] + 1.f) * isd;
                float w1 = rsqrtf((float)cur[s1] + 1.f) * isd;
                float w2_ = rsqrtf((float)cur[s2] + 1.f) * isd;
                float w3 = rsqrtf((float)cur[s3] + 1.f) * isd;
                acc += hbuf[s0 * H + f] * w0 + hbuf[s1 * H + f] * w1
                     + hbuf[s2 * H + f] * w2_ + hbuf[s3 * H + f] * w3;
            }
            for (; p < deg; ++p) {
                int s = rowp[p];
                acc += hbuf[s * H + f] * (rsqrtf((float)cur[s] + 1.f) * isd);
            }
            h1[i * H + f] = fmaxf(acc, 0.f);
        }
    }
    grid_sync(bar, 2 * NBLK);

    // ============ phase D: agg2 (Â·h1), @W2 + b2, cosine score ============
    for (int q = 0; q < 4; ++q) {
        int g = b + NBLK * q;
        if (g < NGROUP) {
            int i = g * 4 + w;
            int di = cur[i];
            float isd = rsqrtf((float)di + 1.f);
            float acc = h1[i * H + f] * (isd * isd);
            int deg = min(di, PAD);
            const int* rowp = csrc + i * PAD;
            int p = 0;
            for (; p + 4 <= deg; p += 4) {
                int s0 = rowp[p], s1 = rowp[p + 1], s2 = rowp[p + 2], s3 = rowp[p + 3];
                float w0 = rsqrtf((float)cur[s0] + 1.f) * isd;
                float w1 = rsqrtf((float)cur[s1] + 1.f) * isd;
                float w2_ = rsqrtf((float)cur[s2] + 1.f) * isd;
                float w3 = rsqrtf((float)cur[s3] + 1.f) * isd;
                acc += h1[s0 * H + f] * w0 + h1[s1 * H + f] * w1
                     + h1[s2 * H + f] * w2_ + h1[s3 * H + f] * w3;
            }
            for (; p < deg; ++p) {
                int s = rowp[p];
                acc += h1[s * H + f] * (rsqrtf((float)cur[s] + 1.f) * isd);
            }
            gsh[w * 64 + f] = acc;              // per-wave region: no cross-wave sync needed
            float hv = b2[f];
            #pragma unroll 16
            for (int k = 0; k < 64; ++k) hv += gsh[w * 64 + k] * w2s[k * 64 + f];
            h2[i * H + f] = hv;
            float dp = wred_f(hv * anorm[f]);
            float nn = wred_f(hv * hv);
            if (f == 0) score[i] = dp / fmaxf(sqrtf(nn), 1e-8f);
        }
    }
    grid_sync(bar, 3 * NBLK);

    // ============ phase E: moments (192 blocks); all blocks stage clf weights ============
    float* cwS = (float*)(smem + 17664);     // [128*7]
    float* cbS = (float*)(smem + 21248);
    for (int idx = t; idx < 128 * C_CLS; idx += NT) cwS[idx] = clfW[idx];
    if (t < C_CLS) cbS[t] = clfb[t];
    if (b < MOM_BLKS) {
        float* Msh = (float*)smem;            // [4][16][64]
        float* Dsh = (float*)(smem + 16384);  // [4][16]
        float accM[KTERMS], accD[KTERMS];
        #pragma unroll
        for (int k = 0; k < KTERMS; ++k) { accM[k] = 0.f; accD[k] = 0.f; }
        for (int j = b * 4 + w; j < N_NODES; j += MOM_BLKS * 4) {
            float sj = score[j];
            float wj = expf(-sj * sj);
            float hv = h2[j * H + f];
            float tm = wj * hv, td = wj;
            #pragma unroll
            for (int k = 0; k < KTERMS; ++k) {
                accM[k] += tm; tm *= sj;
                accD[k] += td; td *= sj;
            }
        }
        #pragma unroll
        for (int k = 0; k < KTERMS; ++k) Msh[(w * KTERMS + k) * 64 + f] = accM[k];
        if (f == 0) {
            #pragma unroll
            for (int k = 0; k < KTERMS; ++k) Dsh[w * KTERMS + k] = accD[k];
        }
        __syncthreads();
        for (int idx = t; idx < KTERMS * 64; idx += NT) {
            int k = idx >> 6, ff = idx & 63;
            float sum = Msh[(0 * KTERMS + k) * 64 + ff] + Msh[(1 * KTERMS + k) * 64 + ff]
                      + Msh[(2 * KTERMS + k) * 64 + ff] + Msh[(3 * KTERMS + k) * 64 + ff];
            unsafeAtomicAdd(&M[idx], (double)sum);
        }
        if (t < KTERMS) {
            float sum = Dsh[t] + Dsh[KTERMS + t] + Dsh[2 * KTERMS + t] + Dsh[3 * KTERMS + t];
            unsafeAtomicAdd(&m0[t], (double)sum);
        }
    }
    grid_sync(bar, 4 * NBLK);

    // ============ phase F: z + concat classifier ============
    float* MsS = (float*)smem;               // [16][64]
    float* m0S = (float*)(smem + 4096);      // [16]
    float* zh  = (float*)(smem + 4160);      // [4][128]
    for (int idx = t; idx < KTERMS * 64; idx += NT) MsS[idx] = (float)M[idx];
    if (t < KTERMS) m0S[t] = (float)m0[t];
    __syncthreads();
    for (int q = 0; q < 4; ++q) {
        int g = b + NBLK * q;
        if (g < NGROUP) {
            int i = g * 4 + w;
            float s = score[i];
            float c = expf(-s * s);
            float t2 = 2.f * s;
            float num = 0.f, den = 0.f;
            #pragma unroll
            for (int k = 0; k < KTERMS; ++k) {
                num += c * MsS[k * 64 + f];
                den += c * m0S[k];
                c *= t2 * (1.0f / (float)(k + 1));
            }
            zh[w * 128 + f] = h2[i * H + f];   // per-wave region
            zh[w * 128 + 64 + f] = num / den;
            if (f < C_CLS) {
                float o = cbS[f];
                #pragma unroll 8
                for (int u = 0; u < 128; ++u) o += zh[w * 128 + u] * cwS[u * C_CLS + f];
                out[(size_t)i * C_CLS + f] = o;
            }
        }
    }
}

// ---------------------------------------------------------------- launch
extern "C" void kernel_launch(void* const* d_in, const int* in_sizes, int n_in,
                              void* d_out, int out_size, void* d_ws, size_t ws_size,
                              hipStream_t stream) {
    (void)in_sizes; (void)n_in; (void)out_size; (void)ws_size;
    const float* x    = (const float*)d_in[0];
    const float* W1   = (const float*)d_in[1];
    const float* b1   = (const float*)d_in[2];
    const float* W2   = (const float*)d_in[3];
    const float* b2   = (const float*)d_in[4];
    const float* aux  = (const float*)d_in[5];
    const float* clfW = (const float*)d_in[6];
    const float* clfb = (const float*)d_in[7];
    const int*   ei   = (const int*)d_in[8];
    float* out = (float*)d_out;
    char* ws = (char*)d_ws;

    float*  hbuf  = (float*)(ws + 0);            // 3,072,000
    float*  h1    = (float*)(ws + 3072000);      // 3,072,000
    float*  h2    = (float*)(ws + 6144000);      // 3,072,000
    float*  score = (float*)(ws + 9216000);      // 48,000
    int*    csrc  = (int*)  (ws + 9264000);      // 12000*96*4 = 4,608,000
    // ---- zeroed region (one memset): bar | cur | M | m0
    int*    bar   = (int*)  (ws + 13872000);     // 128 B
    int*    cur   = (int*)  (ws + 13872128);     // 48,000
    double* M     = (double*)(ws + 13920128);    // 8,192
    double* m0    = (double*)(ws + 13928320);    // 128
    const size_t zero_off = 13872000, zero_sz = 128 + 48000 + 8192 + 128;

    hipMemsetAsync(ws + zero_off, 0, zero_sz, stream);
    fused_k<<<NBLK, NT, 0, stream>>>(x, W1, b1, W2, b2, aux, clfW, clfb, ei,
                                     hbuf, h1, h2, score, csrc, cur, M, m0, bar, out);
}

// Round 5
// 394.311 us; speedup vs baseline: 1.8556x; 1.8556x over previous
//
#include <hip/hip_runtime.h>
#include <hip/hip_bf16.h>

#define N_NODES 12000
#define N_EDGES 384000
#define F_IN 512
#define H 64
#define C_CLS 7
#define KTERMS 16
#define PAD 96
#define NBLK 768
#define NT 256
#define GEMM_BLKS 384
#define NGROUP (N_NODES / 4)
#define MOM_BLKS 192

__device__ __forceinline__ float wred_f(float x) {
    #pragma unroll
    for (int o = 32; o > 0; o >>= 1) x += __shfl_xor(x, o);
    return x;
}

// grid-wide barrier. Arrive: release fetch_add (one L2 writeback per block).
// Spin: RELAXED loads (no per-iteration invalidate!) + s_sleep backoff.
// Exit: ONE agent-scope acquire fence (single L1/L2 invalidate), then block sync.
__device__ __forceinline__ void grid_sync(int* bar, int target) {
    __syncthreads();
    if (threadIdx.x == 0) {
        __hip_atomic_fetch_add(bar, 1, __ATOMIC_RELEASE, __HIP_MEMORY_SCOPE_AGENT);
        while (__hip_atomic_load(bar, __ATOMIC_RELAXED, __HIP_MEMORY_SCOPE_AGENT) < target)
            __builtin_amdgcn_s_sleep(16);
        __builtin_amdgcn_fence(__ATOMIC_ACQUIRE, "agent");
    }
    __syncthreads();
}

__global__ __launch_bounds__(NT, 4) void fused_k(
        const float* __restrict__ x, const float* __restrict__ W1,
        const float* __restrict__ b1, const float* __restrict__ W2,
        const float* __restrict__ b2, const float* __restrict__ aux,
        const float* __restrict__ clfW, const float* __restrict__ clfb,
        const int* __restrict__ ei,
        float* __restrict__ hbuf, float* __restrict__ h1, float* __restrict__ h2,
        float* __restrict__ score, int* __restrict__ csrc, int* __restrict__ cur,
        double* __restrict__ M, double* __restrict__ m0, int* __restrict__ bar,
        float* __restrict__ out) {
    __shared__ __align__(16) char smem[25600];
    const int b = blockIdx.x, t = threadIdx.x;
    const int f = t & 63, w = t >> 6;

    // ============ phase A: gemm1 (blocks 0..383)  ||  padded-CSR fill ============
    if (b < GEMM_BLKS) {
        if (b * 32 < N_NODES) {
            float* xsT = (float*)smem;            // [64][34]
            float* wsm = (float*)(smem + 8704);   // [64][64]
            const int tx = t & 15, ty = t >> 4;
            const int i0 = b * 32;
            float acc[2][4] = {};
            for (int k0 = 0; k0 < F_IN; k0 += 64) {
                for (int idx = t; idx < 512; idx += NT) {
                    int m = idx >> 4, c4 = idx & 15;
                    float4 v = *(const float4*)(x + (size_t)(i0 + m) * F_IN + k0 + c4 * 4);
                    xsT[(c4 * 4 + 0) * 34 + m] = v.x;
                    xsT[(c4 * 4 + 1) * 34 + m] = v.y;
                    xsT[(c4 * 4 + 2) * 34 + m] = v.z;
                    xsT[(c4 * 4 + 3) * 34 + m] = v.w;
                }
                for (int idx = t; idx < 1024; idx += NT) {
                    int r = idx >> 4, c4 = idx & 15;
                    *(float4*)(&wsm[r * 64 + c4 * 4]) =
                        *(const float4*)(W1 + (size_t)(k0 + r) * H + c4 * 4);
                }
                __syncthreads();
                #pragma unroll
                for (int kk = 0; kk < 64; ++kk) {
                    float2 a = *(const float2*)(&xsT[kk * 34 + ty * 2]);
                    float4 bb = *(const float4*)(&wsm[kk * 64 + tx * 4]);
                    acc[0][0] += a.x * bb.x; acc[0][1] += a.x * bb.y;
                    acc[0][2] += a.x * bb.z; acc[0][3] += a.x * bb.w;
                    acc[1][0] += a.y * bb.x; acc[1][1] += a.y * bb.y;
                    acc[1][2] += a.y * bb.z; acc[1][3] += a.y * bb.w;
                }
                __syncthreads();
            }
            #pragma unroll
            for (int q = 0; q < 2; ++q) {
                float4 v = make_float4(acc[q][0], acc[q][1], acc[q][2], acc[q][3]);
                *(float4*)(hbuf + (size_t)(i0 + ty * 2 + q) * H + tx * 4) = v;
            }
        }
    } else {
        for (int e = (b - GEMM_BLKS) * NT + t; e < N_EDGES; e += (NBLK - GEMM_BLKS) * NT) {
            int s = ei[e];
            int d = ei[N_EDGES + e];
            int pos = atomicAdd(&cur[d], 1);
            if (pos < PAD) csrc[d * PAD + pos] = s;   // overflow guard (P ~ 1e-14)
        }
    }
    grid_sync(bar, NBLK);

    // ============ phase C: stage W2 + aux-norm; agg1 (Â·hbuf + b1, ReLU) ============
    float* w2s   = (float*)smem;             // [64][64]
    float* anorm = (float*)(smem + 16384);   // [64]
    float* gsh   = (float*)(smem + 16640);   // [4][64]
    #pragma unroll
    for (int q = 0; q < 4; ++q) {
        int idx = t + q * NT;
        int r = idx >> 4, c4 = idx & 15;
        *(float4*)(&w2s[r * 64 + c4 * 4]) = *(const float4*)(W2 + r * H + c4 * 4);
    }
    if (t < 64) {
        float av = aux[t];
        float an2 = wred_f(av * av);
        anorm[t] = av * rsqrtf(fmaxf(an2, 1e-24f));
    }
    for (int q = 0; q < 4; ++q) {
        int g = b + NBLK * q;
        if (g < NGROUP) {
            int i = g * 4 + w;
            int di = cur[i];
            float isd = rsqrtf((float)di + 1.f);
            float acc = hbuf[i * H + f] * (isd * isd) + b1[f];
            int deg = min(di, PAD);
            const int* rowp = csrc + i * PAD;
            int p = 0;
            for (; p + 4 <= deg; p += 4) {
                int s0 = rowp[p], s1 = rowp[p + 1], s2 = rowp[p + 2], s3 = rowp[p + 3];
                float w0 = rsqrtf((float)cur[s0] + 1.f) * isd;
                float w1 = rsqrtf((float)cur[s1] + 1.f) * isd;
                float w2_ = rsqrtf((float)cur[s2] + 1.f) * isd;
                float w3 = rsqrtf((float)cur[s3] + 1.f) * isd;
                acc += hbuf[s0 * H + f] * w0 + hbuf[s1 * H + f] * w1
                     + hbuf[s2 * H + f] * w2_ + hbuf[s3 * H + f] * w3;
            }
            for (; p < deg; ++p) {
                int s = rowp[p];
                acc += hbuf[s * H + f] * (rsqrtf((float)cur[s] + 1.f) * isd);
            }
            h1[i * H + f] = fmaxf(acc, 0.f);
        }
    }
    grid_sync(bar, 2 * NBLK);

    // ============ phase D: agg2 (Â·h1), @W2 + b2, cosine score ============
    for (int q = 0; q < 4; ++q) {
        int g = b + NBLK * q;
        if (g < NGROUP) {
            int i = g * 4 + w;
            int di = cur[i];
            float isd = rsqrtf((float)di + 1.f);
            float acc = h1[i * H + f] * (isd * isd);
            int deg = min(di, PAD);
            const int* rowp = csrc + i * PAD;
            int p = 0;
            for (; p + 4 <= deg; p += 4) {
                int s0 = rowp[p], s1 = rowp[p + 1], s2 = rowp[p + 2], s3 = rowp[p + 3];
                float w0 = rsqrtf((float)cur[s0] + 1.f) * isd;
                float w1 = rsqrtf((float)cur[s1] + 1.f) * isd;
                float w2_ = rsqrtf((float)cur[s2] + 1.f) * isd;
                float w3 = rsqrtf((float)cur[s3] + 1.f) * isd;
                acc += h1[s0 * H + f] * w0 + h1[s1 * H + f] * w1
                     + h1[s2 * H + f] * w2_ + h1[s3 * H + f] * w3;
            }
            for (; p < deg; ++p) {
                int s = rowp[p];
                acc += h1[s * H + f] * (rsqrtf((float)cur[s] + 1.f) * isd);
            }
            gsh[w * 64 + f] = acc;              // per-wave region: no cross-wave sync needed
            float hv = b2[f];
            #pragma unroll 16
            for (int k = 0; k < 64; ++k) hv += gsh[w * 64 + k] * w2s[k * 64 + f];
            h2[i * H + f] = hv;
            float dp = wred_f(hv * anorm[f]);
            float nn = wred_f(hv * hv);
            if (f == 0) score[i] = dp / fmaxf(sqrtf(nn), 1e-8f);
        }
    }
    grid_sync(bar, 3 * NBLK);

    // ============ phase E: moments (192 blocks); all blocks stage clf weights ============
    float* cwS = (float*)(smem + 17664);     // [128*7]
    float* cbS = (float*)(smem + 21248);
    for (int idx = t; idx < 128 * C_CLS; idx += NT) cwS[idx] = clfW[idx];
    if (t < C_CLS) cbS[t] = clfb[t];
    if (b < MOM_BLKS) {
        float* Msh = (float*)smem;            // [4][16][64]
        float* Dsh = (float*)(smem + 16384);  // [4][16]
        float accM[KTERMS], accD[KTERMS];
        #pragma unroll
        for (int k = 0; k < KTERMS; ++k) { accM[k] = 0.f; accD[k] = 0.f; }
        for (int j = b * 4 + w; j < N_NODES; j += MOM_BLKS * 4) {
            float sj = score[j];
            float wj = expf(-sj * sj);
            float hv = h2[j * H + f];
            float tm = wj * hv, td = wj;
            #pragma unroll
            for (int k = 0; k < KTERMS; ++k) {
                accM[k] += tm; tm *= sj;
                accD[k] += td; td *= sj;
            }
        }
        #pragma unroll
        for (int k = 0; k < KTERMS; ++k) Msh[(w * KTERMS + k) * 64 + f] = accM[k];
        if (f == 0) {
            #pragma unroll
            for (int k = 0; k < KTERMS; ++k) Dsh[w * KTERMS + k] = accD[k];
        }
        __syncthreads();
        for (int idx = t; idx < KTERMS * 64; idx += NT) {
            int k = idx >> 6, ff = idx & 63;
            float sum = Msh[(0 * KTERMS + k) * 64 + ff] + Msh[(1 * KTERMS + k) * 64 + ff]
                      + Msh[(2 * KTERMS + k) * 64 + ff] + Msh[(3 * KTERMS + k) * 64 + ff];
            unsafeAtomicAdd(&M[idx], (double)sum);
        }
        if (t < KTERMS) {
            float sum = Dsh[t] + Dsh[KTERMS + t] + Dsh[2 * KTERMS + t] + Dsh[3 * KTERMS + t];
            unsafeAtomicAdd(&m0[t], (double)sum);
        }
    }
    grid_sync(bar, 4 * NBLK);

    // ============ phase F: z + concat classifier ============
    float* MsS = (float*)smem;               // [16][64]
    float* m0S = (float*)(smem + 4096);      // [16]
    float* zh  = (float*)(smem + 4160);      // [4][128]
    for (int idx = t; idx < KTERMS * 64; idx += NT) MsS[idx] = (float)M[idx];
    if (t < KTERMS) m0S[t] = (float)m0[t];
    __syncthreads();
    for (int q = 0; q < 4; ++q) {
        int g = b + NBLK * q;
        if (g < NGROUP) {
            int i = g * 4 + w;
            float s = score[i];
            float c = expf(-s * s);
            float t2 = 2.f * s;
            float num = 0.f, den = 0.f;
            #pragma unroll
            for (int k = 0; k < KTERMS; ++k) {
                num += c * MsS[k * 64 + f];
                den += c * m0S[k];
                c *= t2 * (1.0f / (float)(k + 1));
            }
            zh[w * 128 + f] = h2[i * H + f];   // per-wave region
            zh[w * 128 + 64 + f] = num / den;
            if (f < C_CLS) {
                float o = cbS[f];
                #pragma unroll 8
                for (int u = 0; u < 128; ++u) o += zh[w * 128 + u] * cwS[u * C_CLS + f];
                out[(size_t)i * C_CLS + f] = o;
            }
        }
    }
}

// ---------------------------------------------------------------- launch
extern "C" void kernel_launch(void* const* d_in, const int* in_sizes, int n_in,
                              void* d_out, int out_size, void* d_ws, size_t ws_size,
                              hipStream_t stream) {
    (void)in_sizes; (void)n_in; (void)out_size; (void)ws_size;
    const float* x    = (const float*)d_in[0];
    const float* W1   = (const float*)d_in[1];
    const float* b1   = (const float*)d_in[2];
    const float* W2   = (const float*)d_in[3];
    const float* b2   = (const float*)d_in[4];
    const float* aux  = (const float*)d_in[5];
    const float* clfW = (const float*)d_in[6];
    const float* clfb = (const float*)d_in[7];
    const int*   ei   = (const int*)d_in[8];
    float* out = (float*)d_out;
    char* ws = (char*)d_ws;

    float*  hbuf  = (float*)(ws + 0);            // 3,072,000
    float*  h1    = (float*)(ws + 3072000);      // 3,072,000
    float*  h2    = (float*)(ws + 6144000);      // 3,072,000
    float*  score = (float*)(ws + 9216000);      // 48,000
    int*    csrc  = (int*)  (ws + 9264000);      // 12000*96*4 = 4,608,000
    // ---- zeroed region (one memset): bar | cur | M | m0
    int*    bar   = (int*)  (ws + 13872000);     // 128 B
    int*    cur   = (int*)  (ws + 13872128);     // 48,000
    double* M     = (double*)(ws + 13920128);    // 8,192
    double* m0    = (double*)(ws + 13928320);    // 128
    const size_t zero_off = 13872000, zero_sz = 128 + 48000 + 8192 + 128;

    hipMemsetAsync(ws + zero_off, 0, zero_sz, stream);
    fused_k<<<NBLK, NT, 0, stream>>>(x, W1, b1, W2, b2, aux, clfW, clfb, ei,
                                     hbuf, h1, h2, score, csrc, cur, M, m0, bar, out);
}

// Round 6
// 310.065 us; speedup vs baseline: 2.3597x; 1.2717x over previous
//
#include <hip/hip_runtime.h>
#include <hip/hip_bf16.h>

#define N_NODES 12000
#define N_EDGES 384000
#define F_IN 512
#define H 64
#define C_CLS 7
#define KTERMS 16
#define PAD 96
#define NBLK 768
#define NT 256
#define NGROUP (N_NODES / 4)
#define GEMM_BLKS 375
#define MOM_BLKS 48

__device__ __forceinline__ float wred_f(float x) {
    #pragma unroll
    for (int o = 32; o > 0; o >>= 1) x += __shfl_xor(x, o);
    return x;
}

// L3-coherent (sc1) scalar accessors: bypass the non-coherent per-XCD L2.
// No fences needed anywhere — the coherence point always has the data.
__device__ __forceinline__ float ldc(const float* p) {
    return __hip_atomic_load(p, __ATOMIC_RELAXED, __HIP_MEMORY_SCOPE_AGENT);
}
__device__ __forceinline__ void stc(float* p, float v) {
    __hip_atomic_store(p, v, __ATOMIC_RELAXED, __HIP_MEMORY_SCOPE_AGENT);
}
__device__ __forceinline__ int ldi(const int* p) {
    return __hip_atomic_load(p, __ATOMIC_RELAXED, __HIP_MEMORY_SCOPE_AGENT);
}
__device__ __forceinline__ void sti(int* p, int v) {
    __hip_atomic_store(p, v, __ATOMIC_RELAXED, __HIP_MEMORY_SCOPE_AGENT);
}

// grid barrier with ZERO cache-maintenance ops: relaxed add + relaxed poll.
// __syncthreads drains vmcnt for all waves (sc1 stores are then in L3).
__device__ __forceinline__ void grid_sync(int* bar, int target) {
    __syncthreads();
    if (threadIdx.x == 0) {
        __hip_atomic_fetch_add(bar, 1, __ATOMIC_RELAXED, __HIP_MEMORY_SCOPE_AGENT);
        while (__hip_atomic_load(bar, __ATOMIC_RELAXED, __HIP_MEMORY_SCOPE_AGENT) < target)
            __builtin_amdgcn_s_sleep(8);
        asm volatile("" ::: "memory");
    }
    __syncthreads();
}

__global__ __launch_bounds__(NT, 4) void fused_k(
        const float* __restrict__ x, const float* __restrict__ W1,
        const float* __restrict__ b1, const float* __restrict__ W2,
        const float* __restrict__ b2, const float* __restrict__ aux,
        const float* __restrict__ clfW, const float* __restrict__ clfb,
        const int* __restrict__ ei,
        float* __restrict__ hbuf, float* __restrict__ h1, float* __restrict__ h2,
        float* __restrict__ score, int* __restrict__ csrc, int* __restrict__ cur,
        double* __restrict__ M, double* __restrict__ m0, int* __restrict__ bar,
        float* __restrict__ out) {
    __shared__ __align__(16) char smem[25600];
    const int b = blockIdx.x, t = threadIdx.x;
    const int f = t & 63, w = t >> 6;

    // ===== phase A: fill (all blocks), then gemm1 (blocks 0..374, 32-row tiles) =====
    for (int e = b * NT + t; e < N_EDGES; e += NBLK * NT) {
        int s = ei[e];
        int d = ei[N_EDGES + e];
        int pos = __hip_atomic_fetch_add(&cur[d], 1, __ATOMIC_RELAXED, __HIP_MEMORY_SCOPE_AGENT);
        if (pos < PAD) sti(&csrc[d * PAD + pos], s);
    }
    if (b < GEMM_BLKS) {
        float* xsT = (float*)smem;            // [64][34]
        float* wsm = (float*)(smem + 8704);   // [64][64]
        const int tx = t & 15, ty = t >> 4;
        const int i0 = b * 32;
        float acc[2][4] = {};
        for (int k0 = 0; k0 < F_IN; k0 += 64) {
            for (int idx = t; idx < 512; idx += NT) {
                int m = idx >> 4, c4 = idx & 15;
                float4 v = *(const float4*)(x + (size_t)(i0 + m) * F_IN + k0 + c4 * 4);
                xsT[(c4 * 4 + 0) * 34 + m] = v.x;
                xsT[(c4 * 4 + 1) * 34 + m] = v.y;
                xsT[(c4 * 4 + 2) * 34 + m] = v.z;
                xsT[(c4 * 4 + 3) * 34 + m] = v.w;
            }
            for (int idx = t; idx < 1024; idx += NT) {
                int r = idx >> 4, c4 = idx & 15;
                *(float4*)(&wsm[r * 64 + c4 * 4]) =
                    *(const float4*)(W1 + (size_t)(k0 + r) * H + c4 * 4);
            }
            __syncthreads();
            #pragma unroll
            for (int kk = 0; kk < 64; ++kk) {
                float2 a = *(const float2*)(&xsT[kk * 34 + ty * 2]);
                float4 bb = *(const float4*)(&wsm[kk * 64 + tx * 4]);
                acc[0][0] += a.x * bb.x; acc[0][1] += a.x * bb.y;
                acc[0][2] += a.x * bb.z; acc[0][3] += a.x * bb.w;
                acc[1][0] += a.y * bb.x; acc[1][1] += a.y * bb.y;
                acc[1][2] += a.y * bb.z; acc[1][3] += a.y * bb.w;
            }
            __syncthreads();
        }
        #pragma unroll
        for (int q2 = 0; q2 < 2; ++q2) {
            int row = i0 + ty * 2 + q2;
            #pragma unroll
            for (int j = 0; j < 4; ++j)
                stc(&hbuf[(size_t)row * H + tx * 4 + j], acc[q2][j]);
        }
    }
    grid_sync(bar, NBLK);

    // ===== phase C: stage W2+anorm; agg1 = relu(Â·hbuf + b1) =====
    float* w2s   = (float*)smem;             // [64][64]
    float* anorm = (float*)(smem + 16384);   // [64]
    float* gsh   = (float*)(smem + 16640);   // [4][64]
    #pragma unroll
    for (int q = 0; q < 4; ++q) {
        int idx = t + q * NT;
        int r = idx >> 4, c4 = idx & 15;
        *(float4*)(&w2s[r * 64 + c4 * 4]) = *(const float4*)(W2 + r * H + c4 * 4);
    }
    if (t < 64) {
        float av = aux[t];
        float an2 = wred_f(av * av);
        anorm[t] = av * rsqrtf(fmaxf(an2, 1e-24f));
    }
    {
        float bias = b1[f];
        for (int q = 0; q < 4; ++q) {
            int g = b * 4 + q;
            if (g < NGROUP) {
                int i = g * 4 + w;
                int di = ldi(&cur[i]);
                float isd = rsqrtf((float)di + 1.f);
                float acc = ldc(&hbuf[i * H + f]) * (isd * isd) + bias;
                int deg = min(di, PAD);
                const int* rowp = csrc + i * PAD;
                int p = 0;
                for (; p + 8 <= deg; p += 8) {
                    int ss[8]; float ww[8];
                    #pragma unroll
                    for (int u = 0; u < 8; ++u) ss[u] = ldi(&rowp[p + u]);
                    #pragma unroll
                    for (int u = 0; u < 8; ++u)
                        ww[u] = rsqrtf((float)ldi(&cur[ss[u]]) + 1.f) * isd;
                    #pragma unroll
                    for (int u = 0; u < 8; ++u)
                        acc += ldc(&hbuf[ss[u] * H + f]) * ww[u];
                }
                for (; p < deg; ++p) {
                    int s = ldi(&rowp[p]);
                    acc += ldc(&hbuf[s * H + f]) * (rsqrtf((float)ldi(&cur[s]) + 1.f) * isd);
                }
                stc(&h1[i * H + f], fmaxf(acc, 0.f));
            }
        }
    }
    grid_sync(bar, 2 * NBLK);

    // ===== phase D: agg2 = (Â·h1)@W2 + b2, + cosine score =====
    {
        float bias2 = b2[f];
        for (int q = 0; q < 4; ++q) {
            int g = b * 4 + q;
            if (g < NGROUP) {
                int i = g * 4 + w;
                int di = ldi(&cur[i]);
                float isd = rsqrtf((float)di + 1.f);
                float acc = ldc(&h1[i * H + f]) * (isd * isd);
                int deg = min(di, PAD);
                const int* rowp = csrc + i * PAD;
                int p = 0;
                for (; p + 8 <= deg; p += 8) {
                    int ss[8]; float ww[8];
                    #pragma unroll
                    for (int u = 0; u < 8; ++u) ss[u] = ldi(&rowp[p + u]);
                    #pragma unroll
                    for (int u = 0; u < 8; ++u)
                        ww[u] = rsqrtf((float)ldi(&cur[ss[u]]) + 1.f) * isd;
                    #pragma unroll
                    for (int u = 0; u < 8; ++u)
                        acc += ldc(&h1[ss[u] * H + f]) * ww[u];
                }
                for (; p < deg; ++p) {
                    int s = ldi(&rowp[p]);
                    acc += ldc(&h1[s * H + f]) * (rsqrtf((float)ldi(&cur[s]) + 1.f) * isd);
                }
                gsh[w * 64 + f] = acc;
                __builtin_amdgcn_wave_barrier();
                float hv = bias2;
                #pragma unroll 16
                for (int k = 0; k < 64; ++k) hv += gsh[w * 64 + k] * w2s[k * 64 + f];
                stc(&h2[i * H + f], hv);
                float dp = wred_f(hv * anorm[f]);
                float nn = wred_f(hv * hv);
                if (f == 0) stc(&score[i], dp / fmaxf(sqrtf(nn), 1e-8f));
            }
        }
    }
    grid_sync(bar, 3 * NBLK);

    // ===== phase E: moments (48 blocks); all blocks stage clf weights =====
    float* cwS = (float*)(smem + 17664);     // [128*7]
    float* cbS = (float*)(smem + 21248);
    for (int idx = t; idx < 128 * C_CLS; idx += NT) cwS[idx] = clfW[idx];
    if (t < C_CLS) cbS[t] = clfb[t];
    if (b < MOM_BLKS) {
        float* Msh = (float*)smem;            // [4][16][64]
        float* Dsh = (float*)(smem + 16384);  // [4][16]
        float accM[KTERMS], accD[KTERMS];
        #pragma unroll
        for (int k = 0; k < KTERMS; ++k) { accM[k] = 0.f; accD[k] = 0.f; }
        for (int j = b * 4 + w; j < N_NODES; j += MOM_BLKS * 4) {
            float sj = ldc(&score[j]);
            float wj = expf(-sj * sj);
            float hv = ldc(&h2[j * H + f]);
            float tm = wj * hv, td = wj;
            #pragma unroll
            for (int k = 0; k < KTERMS; ++k) {
                accM[k] += tm; tm *= sj;
                accD[k] += td; td *= sj;
            }
        }
        #pragma unroll
        for (int k = 0; k < KTERMS; ++k) Msh[(w * KTERMS + k) * 64 + f] = accM[k];
        if (f == 0) {
            #pragma unroll
            for (int k = 0; k < KTERMS; ++k) Dsh[w * KTERMS + k] = accD[k];
        }
        __syncthreads();
        for (int idx = t; idx < KTERMS * 64; idx += NT) {
            int k = idx >> 6, ff = idx & 63;
            float sum = Msh[(0 * KTERMS + k) * 64 + ff] + Msh[(1 * KTERMS + k) * 64 + ff]
                      + Msh[(2 * KTERMS + k) * 64 + ff] + Msh[(3 * KTERMS + k) * 64 + ff];
            __hip_atomic_fetch_add(&M[idx], (double)sum, __ATOMIC_RELAXED,
                                   __HIP_MEMORY_SCOPE_AGENT);
        }
        if (t < KTERMS) {
            float sum = Dsh[t] + Dsh[KTERMS + t] + Dsh[2 * KTERMS + t] + Dsh[3 * KTERMS + t];
            __hip_atomic_fetch_add(&m0[t], (double)sum, __ATOMIC_RELAXED,
                                   __HIP_MEMORY_SCOPE_AGENT);
        }
    }
    grid_sync(bar, 4 * NBLK);

    // ===== phase F: z + concat classifier =====
    float* MsS = (float*)smem;               // [16][64]
    float* m0S = (float*)(smem + 4096);      // [16]
    float* zh  = (float*)(smem + 4160);      // [4][128]
    for (int idx = t; idx < KTERMS * 64; idx += NT)
        MsS[idx] = (float)__hip_atomic_load(&M[idx], __ATOMIC_RELAXED,
                                            __HIP_MEMORY_SCOPE_AGENT);
    if (t < KTERMS)
        m0S[t] = (float)__hip_atomic_load(&m0[t], __ATOMIC_RELAXED,
                                          __HIP_MEMORY_SCOPE_AGENT);
    __syncthreads();
    for (int q = 0; q < 4; ++q) {
        int g = b * 4 + q;
        if (g < NGROUP) {
            int i = g * 4 + w;
            float s = ldc(&score[i]);
            float c = expf(-s * s);
            float t2 = 2.f * s;
            float num = 0.f, den = 0.f;
            #pragma unroll
            for (int k = 0; k < KTERMS; ++k) {
                num += c * MsS[k * 64 + f];
                den += c * m0S[k];
                c *= t2 * (1.0f / (float)(k + 1));
            }
            zh[w * 128 + f] = ldc(&h2[i * H + f]);
            zh[w * 128 + 64 + f] = num / den;
            __builtin_amdgcn_wave_barrier();
            if (f < C_CLS) {
                float o = cbS[f];
                #pragma unroll 8
                for (int u = 0; u < 128; ++u) o += zh[w * 128 + u] * cwS[u * C_CLS + f];
                out[(size_t)i * C_CLS + f] = o;
            }
            __builtin_amdgcn_wave_barrier();
        }
    }
}

// ---------------------------------------------------------------- launch
extern "C" void kernel_launch(void* const* d_in, const int* in_sizes, int n_in,
                              void* d_out, int out_size, void* d_ws, size_t ws_size,
                              hipStream_t stream) {
    (void)in_sizes; (void)n_in; (void)out_size; (void)ws_size;
    const float* x    = (const float*)d_in[0];
    const float* W1   = (const float*)d_in[1];
    const float* b1   = (const float*)d_in[2];
    const float* W2   = (const float*)d_in[3];
    const float* b2   = (const float*)d_in[4];
    const float* aux  = (const float*)d_in[5];
    const float* clfW = (const float*)d_in[6];
    const float* clfb = (const float*)d_in[7];
    const int*   ei   = (const int*)d_in[8];
    float* out = (float*)d_out;
    char* ws = (char*)d_ws;

    float*  hbuf  = (float*)(ws + 0);            // 3,072,000
    float*  h1    = (float*)(ws + 3072000);      // 3,072,000
    float*  h2    = (float*)(ws + 6144000);      // 3,072,000
    float*  score = (float*)(ws + 9216000);      // 48,000
    int*    csrc  = (int*)  (ws + 9264000);      // 12000*96*4 = 4,608,000
    // ---- zeroed region (one memset): bar | cur | M | m0
    int*    bar   = (int*)  (ws + 13872000);     // 128 B
    int*    cur   = (int*)  (ws + 13872128);     // 48,000
    double* M     = (double*)(ws + 13920128);    // 8,192
    double* m0    = (double*)(ws + 13928320);    // 128
    const size_t zero_off = 13872000, zero_sz = 128 + 48000 + 8192 + 128;

    hipMemsetAsync(ws + zero_off, 0, zero_sz, stream);
    fused_k<<<NBLK, NT, 0, stream>>>(x, W1, b1, W2, b2, aux, clfW, clfb, ei,
                                     hbuf, h1, h2, score, csrc, cur, M, m0, bar, out);
}

// Round 7
// 306.485 us; speedup vs baseline: 2.3873x; 1.0117x over previous
//
#include <hip/hip_runtime.h>
#include <hip/hip_bf16.h>

#define N_NODES 12000
#define N_EDGES 384000
#define F_IN 512
#define H 64
#define C_CLS 7
#define KTERMS 16
#define PAD 96
#define NBLK 768
#define NT 256
#define NGROUP (N_NODES / 4)
#define GEMM_BLKS 750
#define MOM_BLKS 64
#define SSTR 32   // score stride (floats): one 128B line per node, single writer

__device__ __forceinline__ float wred_f(float x) {
    #pragma unroll
    for (int o = 32; o > 0; o >>= 1) x += __shfl_xor(x, o);
    return x;
}

// sc1 write-through store: data reaches L3 (agent coherence point).
__device__ __forceinline__ void stc(float* p, float v) {
    __hip_atomic_store(p, v, __ATOMIC_RELAXED, __HIP_MEMORY_SCOPE_AGENT);
}

// grid barrier: relaxed add + relaxed poll, zero cache-maintenance ops.
// __syncthreads drains vmcnt (all sc1 stores retired to L3) before arrive.
__device__ __forceinline__ void grid_sync(int* bar, int target) {
    __syncthreads();
    if (threadIdx.x == 0) {
        __hip_atomic_fetch_add(bar, 1, __ATOMIC_RELAXED, __HIP_MEMORY_SCOPE_AGENT);
        while (__hip_atomic_load(bar, __ATOMIC_RELAXED, __HIP_MEMORY_SCOPE_AGENT) < target)
            __builtin_amdgcn_s_sleep(8);
        asm volatile("" ::: "memory");
    }
    __syncthreads();
}

__global__ __launch_bounds__(NT, 4) void fused_k(
        const float* __restrict__ x, const float* __restrict__ W1,
        const float* __restrict__ b1, const float* __restrict__ W2,
        const float* __restrict__ b2, const float* __restrict__ aux,
        const float* __restrict__ clfW, const float* __restrict__ clfb,
        const int* __restrict__ ei,
        float* __restrict__ hbuf, float* __restrict__ h1, float* __restrict__ h2,
        float* __restrict__ score, int* __restrict__ csrc, int* __restrict__ cur,
        double* __restrict__ M, double* __restrict__ m0, int* __restrict__ bar,
        float* __restrict__ out) {
    __shared__ __align__(16) char smem[25600];
    const int b = blockIdx.x, t = threadIdx.x;
    const int f = t & 63, w = t >> 6;

    // ===== phase A: padded-CSR fill (all blocks, atomics at L3), then gemm1 =====
    for (int e = b * NT + t; e < N_EDGES; e += NBLK * NT) {
        int s = ei[e];
        int d = ei[N_EDGES + e];
        int pos = __hip_atomic_fetch_add(&cur[d], 1, __ATOMIC_RELAXED,
                                         __HIP_MEMORY_SCOPE_AGENT);
        // atomic_exchange: executes at L3, no stale L2 allocation (multi-writer lines)
        if (pos < PAD)
            (void)__hip_atomic_exchange(&csrc[d * PAD + pos], s, __ATOMIC_RELAXED,
                                        __HIP_MEMORY_SCOPE_AGENT);
    }
    if (b < GEMM_BLKS) {
        // 16-row tile: i0 = b*16
        float* xsT = (float*)smem;            // [64][19] padded
        float* wsm = (float*)(smem + 4864);   // [64][64]
        const int tx = t & 15, ty = t >> 4;   // tx: col-group, ty: row
        const int i0 = b * 16;
        float acc[4] = {};
        for (int k0 = 0; k0 < F_IN; k0 += 64) {
            {   // x tile 16x64 -> transposed [kk][m]
                int m = t >> 4, c4 = t & 15;
                float4 v = *(const float4*)(x + (size_t)(i0 + m) * F_IN + k0 + c4 * 4);
                xsT[(c4 * 4 + 0) * 19 + m] = v.x;
                xsT[(c4 * 4 + 1) * 19 + m] = v.y;
                xsT[(c4 * 4 + 2) * 19 + m] = v.z;
                xsT[(c4 * 4 + 3) * 19 + m] = v.w;
            }
            #pragma unroll
            for (int q = 0; q < 4; ++q) {     // W1 tile 64x64
                int idx = t + q * NT;
                int r = idx >> 4, c4 = idx & 15;
                *(float4*)(&wsm[r * 64 + c4 * 4]) =
                    *(const float4*)(W1 + (size_t)(k0 + r) * H + c4 * 4);
            }
            __syncthreads();
            #pragma unroll
            for (int kk = 0; kk < 64; ++kk) {
                float a = xsT[kk * 19 + ty];
                float4 bb = *(const float4*)(&wsm[kk * 64 + tx * 4]);
                acc[0] += a * bb.x; acc[1] += a * bb.y;
                acc[2] += a * bb.z; acc[3] += a * bb.w;
            }
            __syncthreads();
        }
        #pragma unroll
        for (int j = 0; j < 4; ++j)
            stc(&hbuf[(size_t)(i0 + ty) * H + tx * 4 + j], acc[j]);
    }
    grid_sync(bar, NBLK);

    // ===== phase C: stage W2+anorm; agg1 = relu(Â·hbuf + b1)  [cached gathers] =====
    float* w2s   = (float*)smem;             // [64][64]
    float* anorm = (float*)(smem + 16384);   // [64]
    float* gsh   = (float*)(smem + 16640);   // [4][64]
    #pragma unroll
    for (int q = 0; q < 4; ++q) {
        int idx = t + q * NT;
        int r = idx >> 4, c4 = idx & 15;
        *(float4*)(&w2s[r * 64 + c4 * 4]) = *(const float4*)(W2 + r * H + c4 * 4);
    }
    if (t < 64) {
        float av = aux[t];
        float an2 = wred_f(av * av);
        anorm[t] = av * rsqrtf(fmaxf(an2, 1e-24f));
    }
    {
        float bias = b1[f];
        for (int q = 0; q < 4; ++q) {
            int g = b * 4 + q;
            if (g < NGROUP) {
                int i = g * 4 + w;
                int di = cur[i];
                float isd = rsqrtf((float)di + 1.f);
                float acc = hbuf[i * H + f] * (isd * isd) + bias;
                int deg = min(di, PAD);
                const int* rowp = csrc + i * PAD;
                int p = 0;
                for (; p + 8 <= deg; p += 8) {
                    int ss[8]; float ww[8];
                    #pragma unroll
                    for (int u = 0; u < 8; ++u) ss[u] = rowp[p + u];
                    #pragma unroll
                    for (int u = 0; u < 8; ++u)
                        ww[u] = rsqrtf((float)cur[ss[u]] + 1.f) * isd;
                    #pragma unroll
                    for (int u = 0; u < 8; ++u)
                        acc += hbuf[ss[u] * H + f] * ww[u];
                }
                for (; p < deg; ++p) {
                    int s = rowp[p];
                    acc += hbuf[s * H + f] * (rsqrtf((float)cur[s] + 1.f) * isd);
                }
                stc(&h1[i * H + f], fmaxf(acc, 0.f));
            }
        }
    }
    grid_sync(bar, 2 * NBLK);

    // ===== phase D: agg2 = (Â·h1)@W2 + b2, + cosine score  [cached gathers] =====
    {
        float bias2 = b2[f];
        for (int q = 0; q < 4; ++q) {
            int g = b * 4 + q;
            if (g < NGROUP) {
                int i = g * 4 + w;
                int di = cur[i];
                float isd = rsqrtf((float)di + 1.f);
                float acc = h1[i * H + f] * (isd * isd);
                int deg = min(di, PAD);
                const int* rowp = csrc + i * PAD;
                int p = 0;
                for (; p + 8 <= deg; p += 8) {
                    int ss[8]; float ww[8];
                    #pragma unroll
                    for (int u = 0; u < 8; ++u) ss[u] = rowp[p + u];
                    #pragma unroll
                    for (int u = 0; u < 8; ++u)
                        ww[u] = rsqrtf((float)cur[ss[u]] + 1.f) * isd;
                    #pragma unroll
                    for (int u = 0; u < 8; ++u)
                        acc += h1[ss[u] * H + f] * ww[u];
                }
                for (; p < deg; ++p) {
                    int s = rowp[p];
                    acc += h1[s * H + f] * (rsqrtf((float)cur[s] + 1.f) * isd);
                }
                gsh[w * 64 + f] = acc;
                __builtin_amdgcn_wave_barrier();
                float hv = bias2;
                #pragma unroll 16
                for (int k = 0; k < 64; ++k) hv += gsh[w * 64 + k] * w2s[k * 64 + f];
                stc(&h2[i * H + f], hv);
                float dp = wred_f(hv * anorm[f]);
                float nn = wred_f(hv * hv);
                if (f == 0) stc(&score[i * SSTR], dp / fmaxf(sqrtf(nn), 1e-8f));
            }
        }
    }
    grid_sync(bar, 3 * NBLK);

    // ===== phase E: moments (64 blocks); all blocks stage clf weights =====
    float* cwS = (float*)(smem + 17664);     // [128*7]
    float* cbS = (float*)(smem + 21248);
    for (int idx = t; idx < 128 * C_CLS; idx += NT) cwS[idx] = clfW[idx];
    if (t < C_CLS) cbS[t] = clfb[t];
    if (b < MOM_BLKS) {
        float* Msh = (float*)smem;            // [4][16][64]
        float* Dsh = (float*)(smem + 16384);  // [4][16]
        float accM[KTERMS], accD[KTERMS];
        #pragma unroll
        for (int k = 0; k < KTERMS; ++k) { accM[k] = 0.f; accD[k] = 0.f; }
        for (int j = b * 4 + w; j < N_NODES; j += MOM_BLKS * 4) {
            float sj = score[j * SSTR];
            float wj = expf(-sj * sj);
            float hv = h2[j * H + f];
            float tm = wj * hv, td = wj;
            #pragma unroll
            for (int k = 0; k < KTERMS; ++k) {
                accM[k] += tm; tm *= sj;
                accD[k] += td; td *= sj;
            }
        }
        #pragma unroll
        for (int k = 0; k < KTERMS; ++k) Msh[(w * KTERMS + k) * 64 + f] = accM[k];
        if (f == 0) {
            #pragma unroll
            for (int k = 0; k < KTERMS; ++k) Dsh[w * KTERMS + k] = accD[k];
        }
        __syncthreads();
        for (int idx = t; idx < KTERMS * 64; idx += NT) {
            int k = idx >> 6, ff = idx & 63;
            float sum = Msh[(0 * KTERMS + k) * 64 + ff] + Msh[(1 * KTERMS + k) * 64 + ff]
                      + Msh[(2 * KTERMS + k) * 64 + ff] + Msh[(3 * KTERMS + k) * 64 + ff];
            __hip_atomic_fetch_add(&M[idx], (double)sum, __ATOMIC_RELAXED,
                                   __HIP_MEMORY_SCOPE_AGENT);
        }
        if (t < KTERMS) {
            float sum = Dsh[t] + Dsh[KTERMS + t] + Dsh[2 * KTERMS + t] + Dsh[3 * KTERMS + t];
            __hip_atomic_fetch_add(&m0[t], (double)sum, __ATOMIC_RELAXED,
                                   __HIP_MEMORY_SCOPE_AGENT);
        }
    }
    grid_sync(bar, 4 * NBLK);

    // ===== phase F: z + concat classifier  [cached reads] =====
    float* MsS = (float*)smem;               // [16][64]
    float* m0S = (float*)(smem + 4096);      // [16]
    float* zh  = (float*)(smem + 4160);      // [4][128]
    for (int idx = t; idx < KTERMS * 64; idx += NT) MsS[idx] = (float)M[idx];
    if (t < KTERMS) m0S[t] = (float)m0[t];
    __syncthreads();
    for (int q = 0; q < 4; ++q) {
        int g = b * 4 + q;
        if (g < NGROUP) {
            int i = g * 4 + w;
            float s = score[i * SSTR];
            float c = expf(-s * s);
            float t2 = 2.f * s;
            float num = 0.f, den = 0.f;
            #pragma unroll
            for (int k = 0; k < KTERMS; ++k) {
                num += c * MsS[k * 64 + f];
                den += c * m0S[k];
                c *= t2 * (1.0f / (float)(k + 1));
            }
            zh[w * 128 + f] = h2[i * H + f];
            zh[w * 128 + 64 + f] = num / den;
            __builtin_amdgcn_wave_barrier();
            if (f < C_CLS) {
                float o = cbS[f];
                #pragma unroll 8
                for (int u = 0; u < 128; ++u) o += zh[w * 128 + u] * cwS[u * C_CLS + f];
                out[(size_t)i * C_CLS + f] = o;
            }
            __builtin_amdgcn_wave_barrier();
        }
    }
}

// ---------------------------------------------------------------- launch
extern "C" void kernel_launch(void* const* d_in, const int* in_sizes, int n_in,
                              void* d_out, int out_size, void* d_ws, size_t ws_size,
                              hipStream_t stream) {
    (void)in_sizes; (void)n_in; (void)out_size; (void)ws_size;
    const float* x    = (const float*)d_in[0];
    const float* W1   = (const float*)d_in[1];
    const float* b1   = (const float*)d_in[2];
    const float* W2   = (const float*)d_in[3];
    const float* b2   = (const float*)d_in[4];
    const float* aux  = (const float*)d_in[5];
    const float* clfW = (const float*)d_in[6];
    const float* clfb = (const float*)d_in[7];
    const int*   ei   = (const int*)d_in[8];
    float* out = (float*)d_out;
    char* ws = (char*)d_ws;

    float*  hbuf  = (float*)(ws + 0);            // 3,072,000
    float*  h1    = (float*)(ws + 3072000);      // 3,072,000
    float*  h2    = (float*)(ws + 6144000);      // 3,072,000
    float*  score = (float*)(ws + 9216000);      // 12000*32*4 = 1,536,000 (padded lines)
    int*    csrc  = (int*)  (ws + 10752000);     // 12000*96*4 = 4,608,000
    // ---- zeroed region (one memset): bar | cur | M | m0
    int*    bar   = (int*)  (ws + 15360000);     // 128
    int*    cur   = (int*)  (ws + 15360128);     // 48,000
    double* M     = (double*)(ws + 15408128);    // 8,192
    double* m0    = (double*)(ws + 15416320);    // 128
    const size_t zero_off = 15360000, zero_sz = 128 + 48000 + 8192 + 128;

    hipMemsetAsync(ws + zero_off, 0, zero_sz, stream);
    fused_k<<<NBLK, NT, 0, stream>>>(x, W1, b1, W2, b2, aux, clfW, clfb, ei,
                                     hbuf, h1, h2, score, csrc, cur, M, m0, bar, out);
}

// Round 8
// 186.019 us; speedup vs baseline: 3.9333x; 1.6476x over previous
//
#include <hip/hip_runtime.h>
#include <hip/hip_bf16.h>

#define N_NODES 12000
#define N_EDGES 384000
#define F_IN 512
#define H 64
#define C_CLS 7
#define KTERMS 16
#define PAD 96
#define NBLK 768
#define NT 256
#define NGROUP 3000
#define GEMM_BLKS 750
#define SSTR 32   // score stride (floats): one 128B line per node

__device__ __forceinline__ float wred_f(float x) {
    #pragma unroll
    for (int o = 32; o > 0; o >>= 1) x += __shfl_xor(x, o);
    return x;
}

// sc1 write-through store: data reaches L3 (agent coherence point).
__device__ __forceinline__ void stc(float* p, float v) {
    __hip_atomic_store(p, v, __ATOMIC_RELAXED, __HIP_MEMORY_SCOPE_AGENT);
}

// Striped tree barrier, zero cache-maintenance ops, low poll pressure.
// bar layout (ints): stripeCtr[s]=bar[s*32] (s<8), root=bar[320],
// relFlag[s]=bar[512+s*32]. All zeroed per launch; generations 1,2,3.
__device__ __forceinline__ void grid_sync(int* bar, int gen) {
    __syncthreads();
    if (threadIdx.x == 0) {
        const int s = blockIdx.x & 7;
        int pos = __hip_atomic_fetch_add(&bar[s * 32], 1, __ATOMIC_RELAXED,
                                         __HIP_MEMORY_SCOPE_AGENT);
        if (pos == 96 * gen - 1) {                 // last arriver of this stripe
            int r = __hip_atomic_fetch_add(&bar[320], 1, __ATOMIC_RELAXED,
                                           __HIP_MEMORY_SCOPE_AGENT);
            if (r == 8 * gen - 1) {                // last stripe overall -> release
                #pragma unroll
                for (int k = 0; k < 8; ++k)
                    __hip_atomic_store(&bar[512 + k * 32], gen, __ATOMIC_RELAXED,
                                       __HIP_MEMORY_SCOPE_AGENT);
            }
        }
        int it = 0;
        while (__hip_atomic_load(&bar[512 + s * 32], __ATOMIC_RELAXED,
                                 __HIP_MEMORY_SCOPE_AGENT) < gen) {
            if (it < 2)      __builtin_amdgcn_s_sleep(2);
            else if (it < 6) __builtin_amdgcn_s_sleep(16);
            else             __builtin_amdgcn_s_sleep(64);
            ++it;
        }
        asm volatile("" ::: "memory");
    }
    __syncthreads();
}

// Lane-distributed CSR gather: lane e preloads index+weight of edge e,
// then a shfl-broadcast loop issues all row loads back-to-back.
__device__ __forceinline__ float gather_row(const float* __restrict__ hin,
                                            const int* __restrict__ cur,
                                            const int* __restrict__ rowp,
                                            int deg, float isd, int f) {
    float acc = 0.f;
    int sidx = 0; float swt = 0.f;
    if (f < deg) {
        int sv = rowp[f];
        sidx = sv;
        swt = rsqrtf((float)cur[sv] + 1.f) * isd;
    }
    int d1 = min(deg, 64);
    for (int e = 0; e < d1; ++e) {
        int ss = __shfl(sidx, e);
        float we = __shfl(swt, e);
        acc += hin[ss * H + f] * we;
    }
    if (deg > 64) {
        int rem = deg - 64;
        int sidx2 = 0; float swt2 = 0.f;
        if (f < rem) {
            int sv = rowp[64 + f];
            sidx2 = sv;
            swt2 = rsqrtf((float)cur[sv] + 1.f) * isd;
        }
        for (int e = 0; e < rem; ++e) {
            int ss = __shfl(sidx2, e);
            float we = __shfl(swt2, e);
            acc += hin[ss * H + f] * we;
        }
    }
    return acc;
}

__global__ __launch_bounds__(NT, 4) void fused_k(
        const float* __restrict__ x, const float* __restrict__ W1,
        const float* __restrict__ b1, const float* __restrict__ W2,
        const float* __restrict__ b2, const float* __restrict__ aux,
        const float* __restrict__ clfW, const float* __restrict__ clfb,
        const int* __restrict__ ei,
        float* __restrict__ hbuf, float* __restrict__ h1, float* __restrict__ h2,
        float* __restrict__ score, int* __restrict__ csrc, int* __restrict__ cur,
        double* __restrict__ M, double* __restrict__ m0, int* __restrict__ bar,
        float* __restrict__ out) {
    __shared__ __align__(16) char smem[25600];
    const int b = blockIdx.x, t = threadIdx.x;
    const int f = t & 63, w = t >> 6;

    // ===== phase A: padded-CSR fill (all blocks, atomics at L3), then gemm1 =====
    for (int e = b * NT + t; e < N_EDGES; e += NBLK * NT) {
        int s = ei[e];
        int d = ei[N_EDGES + e];
        int pos = __hip_atomic_fetch_add(&cur[d], 1, __ATOMIC_RELAXED,
                                         __HIP_MEMORY_SCOPE_AGENT);
        if (pos < PAD)
            (void)__hip_atomic_exchange(&csrc[d * PAD + pos], s, __ATOMIC_RELAXED,
                                        __HIP_MEMORY_SCOPE_AGENT);
    }
    if (b < GEMM_BLKS) {
        float* xsT = (float*)smem;            // [64][19] padded
        float* wsm = (float*)(smem + 4864);   // [64][64]
        const int tx = t & 15, ty = t >> 4;
        const int i0 = b * 16;
        float acc[4] = {};
        for (int k0 = 0; k0 < F_IN; k0 += 64) {
            {
                int m = t >> 4, c4 = t & 15;
                float4 v = *(const float4*)(x + (size_t)(i0 + m) * F_IN + k0 + c4 * 4);
                xsT[(c4 * 4 + 0) * 19 + m] = v.x;
                xsT[(c4 * 4 + 1) * 19 + m] = v.y;
                xsT[(c4 * 4 + 2) * 19 + m] = v.z;
                xsT[(c4 * 4 + 3) * 19 + m] = v.w;
            }
            #pragma unroll
            for (int q = 0; q < 4; ++q) {
                int idx = t + q * NT;
                int r = idx >> 4, c4 = idx & 15;
                *(float4*)(&wsm[r * 64 + c4 * 4]) =
                    *(const float4*)(W1 + (size_t)(k0 + r) * H + c4 * 4);
            }
            __syncthreads();
            #pragma unroll
            for (int kk = 0; kk < 64; ++kk) {
                float a = xsT[kk * 19 + ty];
                float4 bb = *(const float4*)(&wsm[kk * 64 + tx * 4]);
                acc[0] += a * bb.x; acc[1] += a * bb.y;
                acc[2] += a * bb.z; acc[3] += a * bb.w;
            }
            __syncthreads();
        }
        #pragma unroll
        for (int j = 0; j < 4; ++j)
            stc(&hbuf[(size_t)(i0 + ty) * H + tx * 4 + j], acc[j]);
    }
    grid_sync(bar, 1);

    // ===== phase C: stage W2+anorm; agg1 = relu(Â·hbuf + b1) =====
    float* w2s   = (float*)smem;             // [64][64] @0
    float* gsh   = (float*)(smem + 16640);   // [4][64]
    float* anorm = (float*)(smem + 17664);   // [64]
    #pragma unroll
    for (int q = 0; q < 4; ++q) {
        int idx = t + q * NT;
        int r = idx >> 4, c4 = idx & 15;
        *(float4*)(&w2s[r * 64 + c4 * 4]) = *(const float4*)(W2 + r * H + c4 * 4);
    }
    if (t < 64) {
        float av = aux[t];
        float an2 = wred_f(av * av);
        anorm[t] = av * rsqrtf(fmaxf(an2, 1e-24f));
    }
    {
        float bias = b1[f];
        for (int q = 0; q < 4; ++q) {
            int g = b + NBLK * q;
            if (g < NGROUP) {
                int i = g * 4 + w;
                int di = cur[i];
                float isd = rsqrtf((float)di + 1.f);
                int deg = min(di, PAD);
                float acc = hbuf[i * H + f] * (isd * isd) + bias
                          + gather_row(hbuf, cur, csrc + i * PAD, deg, isd, f);
                stc(&h1[i * H + f], fmaxf(acc, 0.f));
            }
        }
    }
    grid_sync(bar, 2);

    // ===== phase D: agg2 = (Â·h1)@W2 + b2, cosine score, + moment accumulation =====
    float accM[KTERMS], accD[KTERMS];
    #pragma unroll
    for (int k = 0; k < KTERMS; ++k) { accM[k] = 0.f; accD[k] = 0.f; }
    {
        float bias2 = b2[f];
        for (int q = 0; q < 4; ++q) {
            int g = b + NBLK * q;
            if (g < NGROUP) {
                int i = g * 4 + w;
                int di = cur[i];
                float isd = rsqrtf((float)di + 1.f);
                int deg = min(di, PAD);
                float acc = h1[i * H + f] * (isd * isd)
                          + gather_row(h1, cur, csrc + i * PAD, deg, isd, f);
                gsh[w * 64 + f] = acc;
                __builtin_amdgcn_wave_barrier();
                float hv = bias2;
                #pragma unroll 16
                for (int k = 0; k < 64; ++k) hv += gsh[w * 64 + k] * w2s[k * 64 + f];
                stc(&h2[i * H + f], hv);
                float dp = wred_f(hv * anorm[f]);
                float nn = wred_f(hv * hv);
                float sc = dp / fmaxf(sqrtf(nn), 1e-8f);
                if (f == 0) stc(&score[i * SSTR], sc);
                float wj = expf(-sc * sc);
                float tm = wj * hv, td = wj;
                #pragma unroll
                for (int k = 0; k < KTERMS; ++k) {
                    accM[k] += tm; tm *= sc;
                    accD[k] += td; td *= sc;
                }
            }
        }
    }
    // block-reduce moments, one f64-atomic flush per block
    __syncthreads();                          // w2s dead from here
    {
        float* Msh = (float*)smem;            // [4][16][64] @0
        float* Dsh = (float*)(smem + 16384);  // [4][16]
        #pragma unroll
        for (int k = 0; k < KTERMS; ++k) Msh[(w * KTERMS + k) * 64 + f] = accM[k];
        if (f == 0) {
            #pragma unroll
            for (int k = 0; k < KTERMS; ++k) Dsh[w * KTERMS + k] = accD[k];
        }
        __syncthreads();
        for (int idx = t; idx < KTERMS * 64; idx += NT) {
            int k = idx >> 6, ff = idx & 63;
            float sum = Msh[(0 * KTERMS + k) * 64 + ff] + Msh[(1 * KTERMS + k) * 64 + ff]
                      + Msh[(2 * KTERMS + k) * 64 + ff] + Msh[(3 * KTERMS + k) * 64 + ff];
            __hip_atomic_fetch_add(&M[idx], (double)sum, __ATOMIC_RELAXED,
                                   __HIP_MEMORY_SCOPE_AGENT);
        }
        if (t < KTERMS) {
            float sum = Dsh[t] + Dsh[KTERMS + t] + Dsh[2 * KTERMS + t] + Dsh[3 * KTERMS + t];
            __hip_atomic_fetch_add(&m0[t], (double)sum, __ATOMIC_RELAXED,
                                   __HIP_MEMORY_SCOPE_AGENT);
        }
    }
    grid_sync(bar, 3);

    // ===== phase F: z + concat classifier =====
    float* MsS = (float*)smem;               // [16][64] @0
    float* m0S = (float*)(smem + 4096);      // [16]
    float* zh  = (float*)(smem + 4224);      // [4][128]
    float* cwS = (float*)(smem + 6272);      // [128*7]
    float* cbS = (float*)(smem + 9856);      // [8]
    for (int idx = t; idx < KTERMS * 64; idx += NT) MsS[idx] = (float)M[idx];
    if (t < KTERMS) m0S[t] = (float)m0[t];
    for (int idx = t; idx < 128 * C_CLS; idx += NT) cwS[idx] = clfW[idx];
    if (t < C_CLS) cbS[t] = clfb[t];
    __syncthreads();
    for (int q = 0; q < 4; ++q) {
        int g = b + NBLK * q;
        if (g < NGROUP) {
            int i = g * 4 + w;
            float s = score[i * SSTR];
            float c = expf(-s * s);
            float t2 = 2.f * s;
            float num = 0.f, den = 0.f;
            #pragma unroll
            for (int k = 0; k < KTERMS; ++k) {
                num += c * MsS[k * 64 + f];
                den += c * m0S[k];
                c *= t2 * (1.0f / (float)(k + 1));
            }
            zh[w * 128 + f] = h2[i * H + f];
            zh[w * 128 + 64 + f] = num / den;
            __builtin_amdgcn_wave_barrier();
            if (f < C_CLS) {
                float o = cbS[f];
                #pragma unroll 8
                for (int u = 0; u < 128; ++u) o += zh[w * 128 + u] * cwS[u * C_CLS + f];
                out[(size_t)i * C_CLS + f] = o;
            }
            __builtin_amdgcn_wave_barrier();
        }
    }
}

// ---------------------------------------------------------------- launch
extern "C" void kernel_launch(void* const* d_in, const int* in_sizes, int n_in,
                              void* d_out, int out_size, void* d_ws, size_t ws_size,
                              hipStream_t stream) {
    (void)in_sizes; (void)n_in; (void)out_size; (void)ws_size;
    const float* x    = (const float*)d_in[0];
    const float* W1   = (const float*)d_in[1];
    const float* b1   = (const float*)d_in[2];
    const float* W2   = (const float*)d_in[3];
    const float* b2   = (const float*)d_in[4];
    const float* aux  = (const float*)d_in[5];
    const float* clfW = (const float*)d_in[6];
    const float* clfb = (const float*)d_in[7];
    const int*   ei   = (const int*)d_in[8];
    float* out = (float*)d_out;
    char* ws = (char*)d_ws;

    float*  hbuf  = (float*)(ws + 0);            // 3,072,000
    float*  h1    = (float*)(ws + 3072000);      // 3,072,000
    float*  h2    = (float*)(ws + 6144000);      // 3,072,000
    float*  score = (float*)(ws + 9216000);      // 1,536,000 (padded lines)
    int*    csrc  = (int*)  (ws + 10752000);     // 4,608,000
    // ---- zeroed region (one memset): bar | cur | M | m0
    int*    bar   = (int*)  (ws + 15360000);     // 4,096
    int*    cur   = (int*)  (ws + 15364096);     // 48,000
    double* M     = (double*)(ws + 15412096);    // 8,192
    double* m0    = (double*)(ws + 15420288);    // 128
    const size_t zero_off = 15360000, zero_sz = 4096 + 48000 + 8192 + 128;

    hipMemsetAsync(ws + zero_off, 0, zero_sz, stream);
    fused_k<<<NBLK, NT, 0, stream>>>(x, W1, b1, W2, b2, aux, clfW, clfb, ei,
                                     hbuf, h1, h2, score, csrc, cur, M, m0, bar, out);
}

// Round 9
// 177.899 us; speedup vs baseline: 4.1128x; 1.0456x over previous
//
#include <hip/hip_runtime.h>
#include <hip/hip_bf16.h>

#define N_NODES 12000
#define N_EDGES 384000
#define F_IN 512
#define H 64
#define C_CLS 7
#define KTERMS 16
#define PAD 96
#define CSTR 32      // cur stride (ints): one 128B line per node -> no atomic line contention
#define MOM_BLKS 96

__device__ __forceinline__ float wred_f(float x) {
    #pragma unroll
    for (int o = 32; o > 0; o >>= 1) x += __shfl_xor(x, o);
    return x;
}

// Lane-distributed CSR gather: lane e preloads index+weight of edge e (coalesced),
// then a shfl-broadcast loop issues all row loads back-to-back (independent).
__device__ __forceinline__ float gather_row(const float* __restrict__ hin,
                                            const int* __restrict__ cur,
                                            const int* __restrict__ rowp,
                                            int deg, float isd, int f) {
    float acc = 0.f;
    int sidx = 0; float swt = 0.f;
    if (f < deg) {
        int sv = rowp[f];
        sidx = sv;
        swt = rsqrtf((float)cur[sv * CSTR] + 1.f) * isd;
    }
    int d1 = min(deg, 64);
    for (int e = 0; e < d1; ++e) {
        int ss = __shfl(sidx, e);
        float we = __shfl(swt, e);
        acc += hin[ss * H + f] * we;
    }
    if (deg > 64) {                       // P ~ 1e-7 per node; PAD=96 cap
        int rem = deg - 64;
        int sidx2 = 0; float swt2 = 0.f;
        if (f < rem) {
            int sv = rowp[64 + f];
            sidx2 = sv;
            swt2 = rsqrtf((float)cur[sv * CSTR] + 1.f) * isd;
        }
        for (int e = 0; e < rem; ++e) {
            int ss = __shfl(sidx2, e);
            float we = __shfl(swt2, e);
            acc += hin[ss * H + f] * we;
        }
    }
    return acc;
}

// ---------------- k1: gemm1 (blocks 0..374) || padded-CSR fill (blocks 375..639)
__global__ __launch_bounds__(256) void k1_gemm_fill(const float* __restrict__ x,
                                                    const float* __restrict__ W1,
                                                    const int* __restrict__ ei,
                                                    float* __restrict__ hbuf,
                                                    int* __restrict__ cur,
                                                    int* __restrict__ csrc) {
    const int b = blockIdx.x, t = threadIdx.x;
    if (b < 375) {
        __shared__ float xsT[64][34];      // [kk][m], padded
        __shared__ float wsm[64][64];      // [kk][f]
        const int tx = t & 15, ty = t >> 4;
        const int i0 = b * 32;
        float acc[2][4] = {};
        for (int k0 = 0; k0 < F_IN; k0 += 64) {
            for (int idx = t; idx < 512; idx += 256) {
                int m = idx >> 4, c4 = idx & 15;
                float4 v = *(const float4*)(x + (size_t)(i0 + m) * F_IN + k0 + c4 * 4);
                xsT[c4 * 4 + 0][m] = v.x;
                xsT[c4 * 4 + 1][m] = v.y;
                xsT[c4 * 4 + 2][m] = v.z;
                xsT[c4 * 4 + 3][m] = v.w;
            }
            for (int idx = t; idx < 1024; idx += 256) {
                int r = idx >> 4, c4 = idx & 15;
                *(float4*)(&wsm[r][c4 * 4]) = *(const float4*)(W1 + (size_t)(k0 + r) * H + c4 * 4);
            }
            __syncthreads();
            #pragma unroll
            for (int kk = 0; kk < 64; ++kk) {
                float2 a = *(const float2*)(&xsT[kk][ty * 2]);
                float4 bb = *(const float4*)(&wsm[kk][tx * 4]);
                acc[0][0] += a.x * bb.x; acc[0][1] += a.x * bb.y;
                acc[0][2] += a.x * bb.z; acc[0][3] += a.x * bb.w;
                acc[1][0] += a.y * bb.x; acc[1][1] += a.y * bb.y;
                acc[1][2] += a.y * bb.z; acc[1][3] += a.y * bb.w;
            }
            __syncthreads();
        }
        #pragma unroll
        for (int q = 0; q < 2; ++q) {
            float4 v = make_float4(acc[q][0], acc[q][1], acc[q][2], acc[q][3]);
            *(float4*)(hbuf + (size_t)(i0 + ty * 2 + q) * H + tx * 4) = v;
        }
    } else {
        for (int e = (b - 375) * 256 + t; e < N_EDGES; e += 265 * 256) {
            int s = ei[e];
            int d = ei[N_EDGES + e];
            int pos = atomicAdd(&cur[d * CSTR], 1);
            if (pos < PAD) csrc[d * PAD + pos] = s;   // overflow guard
        }
    }
}

// ---------------- k2: agg1 = relu(A_hat @ hbuf + b1)
__global__ __launch_bounds__(256) void agg1_k(const float* __restrict__ hbuf,
                                              const float* __restrict__ b1,
                                              const int* __restrict__ cur,
                                              const int* __restrict__ csrc,
                                              float* __restrict__ h1) {
    const int t = threadIdx.x, f = t & 63, w = t >> 6;
    const float bias = b1[f];
    const int base = blockIdx.x * 16;
    for (int q = 0; q < 4; ++q) {
        int i = base + q * 4 + w;          // 750*16 = 12000, always valid
        int di = cur[i * CSTR];
        float isd = rsqrtf((float)di + 1.f);
        int deg = min(di, PAD);
        float acc = hbuf[i * H + f] * (isd * isd) + bias
                  + gather_row(hbuf, cur, csrc + i * PAD, deg, isd, f);
        h1[i * H + f] = fmaxf(acc, 0.f);
    }
}

// ---------------- k3: agg2 = (A_hat @ h1) @ W2 + b2  (+ cosine score)
__global__ __launch_bounds__(256) void agg2_k(const float* __restrict__ h1,
                                              const float* __restrict__ W2,
                                              const float* __restrict__ b2,
                                              const float* __restrict__ aux,
                                              const int* __restrict__ cur,
                                              const int* __restrict__ csrc,
                                              float* __restrict__ h2,
                                              float* __restrict__ score) {
    __shared__ float w2s[64 * 64];
    __shared__ float anorm[64];
    __shared__ float gsh[4 * 64];
    const int t = threadIdx.x, f = t & 63, w = t >> 6;
    #pragma unroll
    for (int q = 0; q < 4; ++q) {
        int idx = t + q * 256;
        int r = idx >> 4, c4 = idx & 15;
        *(float4*)(&w2s[r * 64 + c4 * 4]) = *(const float4*)(W2 + r * H + c4 * 4);
    }
    if (t < 64) {
        float av = aux[t];
        anorm[t] = av * rsqrtf(fmaxf(wred_f(av * av), 1e-24f));
    }
    __syncthreads();
    const float bias2 = b2[f];
    const int base = blockIdx.x * 16;
    for (int q = 0; q < 4; ++q) {
        int i = base + q * 4 + w;
        int di = cur[i * CSTR];
        float isd = rsqrtf((float)di + 1.f);
        int deg = min(di, PAD);
        float acc = h1[i * H + f] * (isd * isd)
                  + gather_row(h1, cur, csrc + i * PAD, deg, isd, f);
        gsh[w * 64 + f] = acc;             // per-wave region
        __builtin_amdgcn_wave_barrier();
        float hv = bias2;
        #pragma unroll 16
        for (int k = 0; k < 64; ++k) hv += gsh[w * 64 + k] * w2s[k * 64 + f];
        h2[i * H + f] = hv;
        float dp = wred_f(hv * anorm[f]);
        float nn = wred_f(hv * hv);
        if (f == 0) score[i] = dp / fmaxf(sqrtf(nn), 1e-8f);
        __builtin_amdgcn_wave_barrier();   // keep next q's gsh write after this q's reads
    }
}

// ---------------- k4: moments M[k][f] = sum_j w_j s_j^k h2[j][f]; m0[k] likewise
__global__ __launch_bounds__(256) void momden_k(const float* __restrict__ h2,
                                                const float* __restrict__ score,
                                                double* __restrict__ M,
                                                double* __restrict__ m0) {
    const int t = threadIdx.x, f = t & 63, g = t >> 6;
    float accM[KTERMS], accD[KTERMS];
    #pragma unroll
    for (int k = 0; k < KTERMS; ++k) { accM[k] = 0.f; accD[k] = 0.f; }
    for (int j = blockIdx.x * 4 + g; j < N_NODES; j += MOM_BLKS * 4) {
        float sj = score[j];
        float wj = expf(-sj * sj);
        float hv = h2[j * H + f];
        float tm = wj * hv, td = wj;
        #pragma unroll
        for (int k = 0; k < KTERMS; ++k) {
            accM[k] += tm; tm *= sj;
            accD[k] += td; td *= sj;
        }
    }
    __shared__ float Msh[4 * KTERMS * 64];
    __shared__ float Dsh[4 * KTERMS];
    #pragma unroll
    for (int k = 0; k < KTERMS; ++k) Msh[(g * KTERMS + k) * 64 + f] = accM[k];
    if (f == 0) {
        #pragma unroll
        for (int k = 0; k < KTERMS; ++k) Dsh[g * KTERMS + k] = accD[k];
    }
    __syncthreads();
    for (int idx = t; idx < KTERMS * 64; idx += 256) {
        int k = idx >> 6, ff = idx & 63;
        float sum = Msh[(0 * KTERMS + k) * 64 + ff] + Msh[(1 * KTERMS + k) * 64 + ff]
                  + Msh[(2 * KTERMS + k) * 64 + ff] + Msh[(3 * KTERMS + k) * 64 + ff];
        unsafeAtomicAdd(&M[idx], (double)sum);
    }
    if (t < KTERMS) {
        float sum = Dsh[t] + Dsh[KTERMS + t] + Dsh[2 * KTERMS + t] + Dsh[3 * KTERMS + t];
        unsafeAtomicAdd(&m0[t], (double)sum);
    }
}

// ---------------- k5: z + concat classifier
__global__ __launch_bounds__(256) void final_k(const float* __restrict__ h2,
                                               const float* __restrict__ score,
                                               const double* __restrict__ M,
                                               const double* __restrict__ m0,
                                               const float* __restrict__ clfW,
                                               const float* __restrict__ clfb,
                                               float* __restrict__ out) {
    __shared__ float Ms[KTERMS * 64];
    __shared__ float m0s[KTERMS];
    __shared__ float cw[128 * C_CLS];
    __shared__ float cb[8];
    __shared__ float zh[4 * 128];
    const int t = threadIdx.x, f = t & 63, w = t >> 6;
    for (int idx = t; idx < KTERMS * 64; idx += 256) Ms[idx] = (float)M[idx];
    if (t < KTERMS) m0s[t] = (float)m0[t];
    for (int idx = t; idx < 128 * C_CLS; idx += 256) cw[idx] = clfW[idx];
    if (t < C_CLS) cb[t] = clfb[t];
    __syncthreads();
    const int base = blockIdx.x * 16;
    for (int q = 0; q < 4; ++q) {
        int i = base + q * 4 + w;
        float s = score[i];
        float c = expf(-s * s);
        float t2 = 2.f * s;
        float num = 0.f, den = 0.f;
        #pragma unroll
        for (int k = 0; k < KTERMS; ++k) {
            num += c * Ms[k * 64 + f];
            den += c * m0s[k];
            c *= t2 * (1.0f / (float)(k + 1));
        }
        zh[w * 128 + f] = h2[i * H + f];   // per-wave region
        zh[w * 128 + 64 + f] = num / den;
        __builtin_amdgcn_wave_barrier();
        if (f < C_CLS) {
            float o = cb[f];
            #pragma unroll 8
            for (int u = 0; u < 128; ++u) o += zh[w * 128 + u] * cw[u * C_CLS + f];
            out[(size_t)i * C_CLS + f] = o;
        }
        __builtin_amdgcn_wave_barrier();
    }
}

// ---------------- launch
extern "C" void kernel_launch(void* const* d_in, const int* in_sizes, int n_in,
                              void* d_out, int out_size, void* d_ws, size_t ws_size,
                              hipStream_t stream) {
    (void)in_sizes; (void)n_in; (void)out_size; (void)ws_size;
    const float* x    = (const float*)d_in[0];
    const float* W1   = (const float*)d_in[1];
    const float* b1   = (const float*)d_in[2];
    const float* W2   = (const float*)d_in[3];
    const float* b2   = (const float*)d_in[4];
    const float* aux  = (const float*)d_in[5];
    const float* clfW = (const float*)d_in[6];
    const float* clfb = (const float*)d_in[7];
    const int*   ei   = (const int*)d_in[8];
    float* out = (float*)d_out;
    char* ws = (char*)d_ws;

    float*  hbuf  = (float*)(ws + 0);            // 3,072,000
    float*  h1    = (float*)(ws + 3072000);      // 3,072,000
    float*  h2    = (float*)(ws + 6144000);      // 3,072,000
    float*  score = (float*)(ws + 9216000);      // 48,000
    int*    csrc  = (int*)  (ws + 9264000);      // 4,608,000
    // ---- zeroed region (one memset): cur (padded) | M | m0
    int*    cur   = (int*)  (ws + 13872000);     // 12000*32*4 = 1,536,000
    double* M     = (double*)(ws + 15408000);    // 8,192
    double* m0    = (double*)(ws + 15416192);    // 128
    const size_t zero_off = 13872000, zero_sz = 1536000 + 8192 + 128;

    hipMemsetAsync(ws + zero_off, 0, zero_sz, stream);
    k1_gemm_fill<<<640, 256, 0, stream>>>(x, W1, ei, hbuf, cur, csrc);
    agg1_k<<<750, 256, 0, stream>>>(hbuf, b1, cur, csrc, h1);
    agg2_k<<<750, 256, 0, stream>>>(h1, W2, b2, aux, cur, csrc, h2, score);
    momden_k<<<MOM_BLKS, 256, 0, stream>>>(h2, score, M, m0);
    final_k<<<750, 256, 0, stream>>>(h2, score, M, m0, clfW, clfb, out);
}

// Round 10
// 98.467 us; speedup vs baseline: 7.4306x; 1.8067x over previous
//
#include <hip/hip_runtime.h>
#include <hip/hip_bf16.h>

#define N_NODES 12000
#define N_EDGES 384000
#define F_IN 512
#define H 64
#define C_CLS 7
#define KTERMS 16
#define PAD 96
#define CSTR 32      // cur stride (ints): one 128B line per node
#define MOM_BLKS 96
#define NB 4         // nodes per agg block (1 per wave)

__device__ __forceinline__ float wred_f(float x) {
    #pragma unroll
    for (int o = 32; o > 0; o >>= 1) x += __shfl_xor(x, o);
    return x;
}

// ---------------- k1: gemm1 (blocks 0..749, 16-row tiles) || CSR fill (750..999)
__global__ __launch_bounds__(256) void k1_gemm_fill(const float* __restrict__ x,
                                                    const float* __restrict__ W1,
                                                    const int* __restrict__ ei,
                                                    float* __restrict__ hbuf,
                                                    int* __restrict__ cur,
                                                    int* __restrict__ csrc) {
    const int b = blockIdx.x, t = threadIdx.x;
    if (b < 750) {
        __shared__ float xsT[64 * 19];     // [kk][m] padded
        __shared__ float wsm[64 * 64];     // [kk][f]
        const int tx = t & 15, ty = t >> 4;
        const int i0 = b * 16;
        float acc[4] = {};
        for (int k0 = 0; k0 < F_IN; k0 += 64) {
            {   // x tile 16x64 -> transposed
                float4 v = *(const float4*)(x + (size_t)(i0 + ty) * F_IN + k0 + tx * 4);
                xsT[(tx * 4 + 0) * 19 + ty] = v.x;
                xsT[(tx * 4 + 1) * 19 + ty] = v.y;
                xsT[(tx * 4 + 2) * 19 + ty] = v.z;
                xsT[(tx * 4 + 3) * 19 + ty] = v.w;
            }
            #pragma unroll
            for (int q = 0; q < 4; ++q) {  // W1 tile 64x64
                int idx = t + q * 256;
                int r = idx >> 4, c4 = idx & 15;
                *(float4*)(&wsm[r * 64 + c4 * 4]) =
                    *(const float4*)(W1 + (size_t)(k0 + r) * H + c4 * 4);
            }
            __syncthreads();
            #pragma unroll
            for (int kk = 0; kk < 64; ++kk) {
                float a = xsT[kk * 19 + ty];
                float4 bb = *(const float4*)(&wsm[kk * 64 + tx * 4]);
                acc[0] += a * bb.x; acc[1] += a * bb.y;
                acc[2] += a * bb.z; acc[3] += a * bb.w;
            }
            __syncthreads();
        }
        *(float4*)(hbuf + (size_t)(i0 + ty) * H + tx * 4) =
            make_float4(acc[0], acc[1], acc[2], acc[3]);
    } else {
        for (int e = (b - 750) * 256 + t; e < N_EDGES; e += 250 * 256) {
            int s = ei[e];
            int d = ei[N_EDGES + e];
            int pos = atomicAdd(&cur[d * CSTR], 1);
            if (pos < PAD) csrc[d * PAD + pos] = s;   // overflow guard
        }
    }
}

// ---------------- k2: invs[i] = rsqrt(deg_i + 1)
__global__ __launch_bounds__(256) void invs_k(const int* __restrict__ cur,
                                              float* __restrict__ invs) {
    int i = blockIdx.x * 256 + threadIdx.x;
    if (i < N_NODES) invs[i] = rsqrtf((float)cur[i * CSTR] + 1.0f);
}

// ---------------- k3: agg1 = relu((Â @ hbuf) + b1)
__global__ __launch_bounds__(256) void agg1_k(const float* __restrict__ hbuf,
                                              const float* __restrict__ b1,
                                              const int* __restrict__ cur,
                                              const int* __restrict__ csrc,
                                              const float* __restrict__ invs,
                                              float* __restrict__ h1) {
    __shared__ int2 sPair[NB * PAD];
    __shared__ int sDeg[NB];
    __shared__ float sIsd[NB];
    const int t = threadIdx.x, f = t & 63, w = t >> 6;
    const int base = blockIdx.x * NB;
    if (t < NB) {
        sDeg[t] = min(cur[(base + t) * CSTR], PAD);
        sIsd[t] = invs[base + t];
    }
    __syncthreads();
    for (int idx = t; idx < NB * PAD; idx += 256) {
        int n = idx / PAD, e = idx - n * PAD;
        if (e < sDeg[n]) {
            int s = csrc[(base + n) * PAD + e];
            sPair[idx] = make_int2(s, __float_as_int(invs[s]));
        }
    }
    __syncthreads();
    const int i = base + w;
    const int deg = sDeg[w];
    const float isd = sIsd[w];
    const int2* pp = sPair + w * PAD;
    float acc = 0.f;
    int e = 0;
    for (; e + 4 <= deg; e += 4) {
        int2 p0 = pp[e], p1 = pp[e + 1], p2 = pp[e + 2], p3 = pp[e + 3];
        acc += hbuf[p0.x * H + f] * __int_as_float(p0.y)
             + hbuf[p1.x * H + f] * __int_as_float(p1.y)
             + hbuf[p2.x * H + f] * __int_as_float(p2.y)
             + hbuf[p3.x * H + f] * __int_as_float(p3.y);
    }
    for (; e < deg; ++e) {
        int2 p = pp[e];
        acc += hbuf[p.x * H + f] * __int_as_float(p.y);
    }
    float res = (acc + hbuf[i * H + f] * isd) * isd + b1[f];
    h1[i * H + f] = fmaxf(res, 0.f);
}

// ---------------- k4: agg2 = (Â @ h1) @ W2 + b2, + cosine score
__global__ __launch_bounds__(256) void agg2_k(const float* __restrict__ h1,
                                              const float* __restrict__ W2,
                                              const float* __restrict__ b2,
                                              const float* __restrict__ aux,
                                              const int* __restrict__ cur,
                                              const int* __restrict__ csrc,
                                              const float* __restrict__ invs,
                                              float* __restrict__ h2,
                                              float* __restrict__ score) {
    __shared__ float w2s[64 * 64];
    __shared__ int2 sPair[NB * PAD];
    __shared__ int sDeg[NB];
    __shared__ float sIsd[NB];
    __shared__ float anorm[64];
    __shared__ float gsh[NB * 64];
    const int t = threadIdx.x, f = t & 63, w = t >> 6;
    const int base = blockIdx.x * NB;
    #pragma unroll
    for (int q = 0; q < 4; ++q) {
        int idx = t + q * 256;
        int r = idx >> 4, c4 = idx & 15;
        *(float4*)(&w2s[r * 64 + c4 * 4]) = *(const float4*)(W2 + r * H + c4 * 4);
    }
    if (t < NB) {
        sDeg[t] = min(cur[(base + t) * CSTR], PAD);
        sIsd[t] = invs[base + t];
    }
    if (t < 64) {
        float av = aux[t];
        anorm[t] = av * rsqrtf(fmaxf(wred_f(av * av), 1e-24f));
    }
    __syncthreads();
    for (int idx = t; idx < NB * PAD; idx += 256) {
        int n = idx / PAD, e = idx - n * PAD;
        if (e < sDeg[n]) {
            int s = csrc[(base + n) * PAD + e];
            sPair[idx] = make_int2(s, __float_as_int(invs[s]));
        }
    }
    __syncthreads();
    const int i = base + w;
    const int deg = sDeg[w];
    const float isd = sIsd[w];
    const int2* pp = sPair + w * PAD;
    float acc = 0.f;
    int e = 0;
    for (; e + 4 <= deg; e += 4) {
        int2 p0 = pp[e], p1 = pp[e + 1], p2 = pp[e + 2], p3 = pp[e + 3];
        acc += h1[p0.x * H + f] * __int_as_float(p0.y)
             + h1[p1.x * H + f] * __int_as_float(p1.y)
             + h1[p2.x * H + f] * __int_as_float(p2.y)
             + h1[p3.x * H + f] * __int_as_float(p3.y);
    }
    for (; e < deg; ++e) {
        int2 p = pp[e];
        acc += h1[p.x * H + f] * __int_as_float(p.y);
    }
    float g = (acc + h1[i * H + f] * isd) * isd;   // aggregated value (pre-W2)
    gsh[w * 64 + f] = g;
    __builtin_amdgcn_wave_barrier();
    float hv = b2[f];
    #pragma unroll 16
    for (int k = 0; k < 64; ++k) hv += gsh[w * 64 + k] * w2s[k * 64 + f];
    h2[i * H + f] = hv;
    float dp = wred_f(hv * anorm[f]);
    float nn = wred_f(hv * hv);
    if (f == 0) score[i] = dp / fmaxf(sqrtf(nn), 1e-8f);
}

// ---------------- k5: moments M[k][f] = sum_j w_j s_j^k h2[j][f]; m0[k] likewise
__global__ __launch_bounds__(256) void momden_k(const float* __restrict__ h2,
                                                const float* __restrict__ score,
                                                double* __restrict__ M,
                                                double* __restrict__ m0) {
    const int t = threadIdx.x, f = t & 63, g = t >> 6;
    float accM[KTERMS], accD[KTERMS];
    #pragma unroll
    for (int k = 0; k < KTERMS; ++k) { accM[k] = 0.f; accD[k] = 0.f; }
    for (int j = blockIdx.x * 4 + g; j < N_NODES; j += MOM_BLKS * 4) {
        float sj = score[j];
        float wj = expf(-sj * sj);
        float hv = h2[j * H + f];
        float tm = wj * hv, td = wj;
        #pragma unroll
        for (int k = 0; k < KTERMS; ++k) {
            accM[k] += tm; tm *= sj;
            accD[k] += td; td *= sj;
        }
    }
    __shared__ float Msh[4 * KTERMS * 64];
    __shared__ float Dsh[4 * KTERMS];
    #pragma unroll
    for (int k = 0; k < KTERMS; ++k) Msh[(g * KTERMS + k) * 64 + f] = accM[k];
    if (f == 0) {
        #pragma unroll
        for (int k = 0; k < KTERMS; ++k) Dsh[g * KTERMS + k] = accD[k];
    }
    __syncthreads();
    for (int idx = t; idx < KTERMS * 64; idx += 256) {
        int k = idx >> 6, ff = idx & 63;
        float sum = Msh[(0 * KTERMS + k) * 64 + ff] + Msh[(1 * KTERMS + k) * 64 + ff]
                  + Msh[(2 * KTERMS + k) * 64 + ff] + Msh[(3 * KTERMS + k) * 64 + ff];
        unsafeAtomicAdd(&M[idx], (double)sum);
    }
    if (t < KTERMS) {
        float sum = Dsh[t] + Dsh[KTERMS + t] + Dsh[2 * KTERMS + t] + Dsh[3 * KTERMS + t];
        unsafeAtomicAdd(&m0[t], (double)sum);
    }
}

// ---------------- k6: z + concat classifier
__global__ __launch_bounds__(256) void final_k(const float* __restrict__ h2,
                                               const float* __restrict__ score,
                                               const double* __restrict__ M,
                                               const double* __restrict__ m0,
                                               const float* __restrict__ clfW,
                                               const float* __restrict__ clfb,
                                               float* __restrict__ out) {
    __shared__ float Ms[KTERMS * 64];
    __shared__ float m0s[KTERMS];
    __shared__ float cw[128 * C_CLS];
    __shared__ float cb[8];
    __shared__ float zh[4 * 128];
    const int t = threadIdx.x, f = t & 63, w = t >> 6;
    for (int idx = t; idx < KTERMS * 64; idx += 256) Ms[idx] = (float)M[idx];
    if (t < KTERMS) m0s[t] = (float)m0[t];
    for (int idx = t; idx < 128 * C_CLS; idx += 256) cw[idx] = clfW[idx];
    if (t < C_CLS) cb[t] = clfb[t];
    __syncthreads();
    const int base = blockIdx.x * 16;
    for (int q = 0; q < 4; ++q) {
        int i = base + q * 4 + w;
        float s = score[i];
        float c = expf(-s * s);
        float t2 = 2.f * s;
        float num = 0.f, den = 0.f;
        #pragma unroll
        for (int k = 0; k < KTERMS; ++k) {
            num += c * Ms[k * 64 + f];
            den += c * m0s[k];
            c *= t2 * (1.0f / (float)(k + 1));
        }
        zh[w * 128 + f] = h2[i * H + f];
        zh[w * 128 + 64 + f] = num / den;
        __builtin_amdgcn_wave_barrier();
        if (f < C_CLS) {
            float o = cb[f];
            #pragma unroll 8
            for (int u = 0; u < 128; ++u) o += zh[w * 128 + u] * cw[u * C_CLS + f];
            out[(size_t)i * C_CLS + f] = o;
        }
        __builtin_amdgcn_wave_barrier();
    }
}

// ---------------- launch
extern "C" void kernel_launch(void* const* d_in, const int* in_sizes, int n_in,
                              void* d_out, int out_size, void* d_ws, size_t ws_size,
                              hipStream_t stream) {
    (void)in_sizes; (void)n_in; (void)out_size; (void)ws_size;
    const float* x    = (const float*)d_in[0];
    const float* W1   = (const float*)d_in[1];
    const float* b1   = (const float*)d_in[2];
    const float* W2   = (const float*)d_in[3];
    const float* b2   = (const float*)d_in[4];
    const float* aux  = (const float*)d_in[5];
    const float* clfW = (const float*)d_in[6];
    const float* clfb = (const float*)d_in[7];
    const int*   ei   = (const int*)d_in[8];
    float* out = (float*)d_out;
    char* ws = (char*)d_ws;

    float*  hbuf  = (float*)(ws + 0);            // 3,072,000
    float*  h1    = (float*)(ws + 3072000);      // 3,072,000
    float*  h2    = (float*)(ws + 6144000);      // 3,072,000
    float*  score = (float*)(ws + 9216000);      // 48,000
    float*  invs  = (float*)(ws + 9264000);      // 48,000
    int*    csrc  = (int*)  (ws + 9312000);      // 4,608,000
    // ---- zeroed region (one memset): cur (padded) | M | m0
    int*    cur   = (int*)  (ws + 13920000);     // 1,536,000
    double* M     = (double*)(ws + 15456000);    // 8,192
    double* m0    = (double*)(ws + 15464192);    // 128
    const size_t zero_off = 13920000, zero_sz = 1536000 + 8192 + 128;

    hipMemsetAsync(ws + zero_off, 0, zero_sz, stream);
    k1_gemm_fill<<<1000, 256, 0, stream>>>(x, W1, ei, hbuf, cur, csrc);
    invs_k<<<47, 256, 0, stream>>>(cur, invs);
    agg1_k<<<N_NODES / NB, 256, 0, stream>>>(hbuf, b1, cur, csrc, invs, h1);
    agg2_k<<<N_NODES / NB, 256, 0, stream>>>(h1, W2, b2, aux, cur, csrc, invs, h2, score);
    momden_k<<<MOM_BLKS, 256, 0, stream>>>(h2, score, M, m0);
    final_k<<<750, 256, 0, stream>>>(h2, score, M, m0, clfW, clfb, out);
}

// Round 11
// 95.459 us; speedup vs baseline: 7.6648x; 1.0315x over previous
//
#include <hip/hip_runtime.h>
#include <hip/hip_bf16.h>

#define N_NODES 12000
#define N_EDGES 384000
#define F_IN 512
#define H 64
#define C_CLS 7
#define KTERMS 16
#define PAD 96
#define CSTR 32      // cur stride (ints): one 128B line per node
#define MOM_BLKS 192
#define NB 4         // nodes per agg block (1 per wave)

__device__ __forceinline__ float wred_f(float x) {
    #pragma unroll
    for (int o = 32; o > 0; o >>= 1) x += __shfl_xor(x, o);
    return x;
}

// ---------------- k0: zero exactly what's read later (replaces 42µs hipMemsetAsync)
__global__ __launch_bounds__(256) void init_k(int* __restrict__ cur,
                                              double* __restrict__ M,
                                              double* __restrict__ m0) {
    int i = blockIdx.x * 256 + threadIdx.x;
    if (i < N_NODES) cur[i * CSTR] = 0;
    if (i < KTERMS * 64) M[i] = 0.0;
    if (i < KTERMS) m0[i] = 0.0;
}

// ---------------- k1: gemm1 (blocks 0..749, 16-row tiles) || CSR fill (750..999)
__global__ __launch_bounds__(256) void k1_gemm_fill(const float* __restrict__ x,
                                                    const float* __restrict__ W1,
                                                    const int* __restrict__ ei,
                                                    float* __restrict__ hbuf,
                                                    int* __restrict__ cur,
                                                    int* __restrict__ csrc) {
    const int b = blockIdx.x, t = threadIdx.x;
    if (b < 750) {
        __shared__ float xsT[64 * 19];     // [kk][m] padded
        __shared__ float wsm[64 * 64];     // [kk][f]
        const int tx = t & 15, ty = t >> 4;
        const int i0 = b * 16;
        float acc[4] = {};
        for (int k0 = 0; k0 < F_IN; k0 += 64) {
            {   // x tile 16x64 -> transposed
                float4 v = *(const float4*)(x + (size_t)(i0 + ty) * F_IN + k0 + tx * 4);
                xsT[(tx * 4 + 0) * 19 + ty] = v.x;
                xsT[(tx * 4 + 1) * 19 + ty] = v.y;
                xsT[(tx * 4 + 2) * 19 + ty] = v.z;
                xsT[(tx * 4 + 3) * 19 + ty] = v.w;
            }
            #pragma unroll
            for (int q = 0; q < 4; ++q) {  // W1 tile 64x64
                int idx = t + q * 256;
                int r = idx >> 4, c4 = idx & 15;
                *(float4*)(&wsm[r * 64 + c4 * 4]) =
                    *(const float4*)(W1 + (size_t)(k0 + r) * H + c4 * 4);
            }
            __syncthreads();
            #pragma unroll
            for (int kk = 0; kk < 64; ++kk) {
                float a = xsT[kk * 19 + ty];
                float4 bb = *(const float4*)(&wsm[kk * 64 + tx * 4]);
                acc[0] += a * bb.x; acc[1] += a * bb.y;
                acc[2] += a * bb.z; acc[3] += a * bb.w;
            }
            __syncthreads();
        }
        *(float4*)(hbuf + (size_t)(i0 + ty) * H + tx * 4) =
            make_float4(acc[0], acc[1], acc[2], acc[3]);
    } else {
        for (int e = (b - 750) * 256 + t; e < N_EDGES; e += 250 * 256) {
            int s = ei[e];
            int d = ei[N_EDGES + e];
            int pos = atomicAdd(&cur[d * CSTR], 1);
            if (pos < PAD) csrc[d * PAD + pos] = s;   // overflow guard
        }
    }
}

// ---------------- k2: agg1 = relu((Â @ hbuf) + b1)
__global__ __launch_bounds__(256) void agg1_k(const float* __restrict__ hbuf,
                                              const float* __restrict__ b1,
                                              const int* __restrict__ cur,
                                              const int* __restrict__ csrc,
                                              float* __restrict__ h1) {
    __shared__ int2 sPair[NB * PAD];
    __shared__ int sDeg[NB];
    __shared__ float sIsd[NB];
    const int t = threadIdx.x, f = t & 63, w = t >> 6;
    const int base = blockIdx.x * NB;
    if (t < NB) {
        int d = cur[(base + t) * CSTR];
        sDeg[t] = min(d, PAD);
        sIsd[t] = rsqrtf((float)d + 1.f);
    }
    __syncthreads();
    for (int idx = t; idx < NB * PAD; idx += 256) {
        int n = idx / PAD, e = idx - n * PAD;
        if (e < sDeg[n]) {
            int s = csrc[(base + n) * PAD + e];
            float ws_ = rsqrtf((float)cur[s * CSTR] + 1.f);
            sPair[idx] = make_int2(s, __float_as_int(ws_));
        }
    }
    __syncthreads();
    const int i = base + w;
    const int deg = sDeg[w];
    const float isd = sIsd[w];
    const int2* pp = sPair + w * PAD;
    float acc = 0.f;
    int e = 0;
    for (; e + 4 <= deg; e += 4) {
        int2 p0 = pp[e], p1 = pp[e + 1], p2 = pp[e + 2], p3 = pp[e + 3];
        acc += hbuf[p0.x * H + f] * __int_as_float(p0.y)
             + hbuf[p1.x * H + f] * __int_as_float(p1.y)
             + hbuf[p2.x * H + f] * __int_as_float(p2.y)
             + hbuf[p3.x * H + f] * __int_as_float(p3.y);
    }
    for (; e < deg; ++e) {
        int2 p = pp[e];
        acc += hbuf[p.x * H + f] * __int_as_float(p.y);
    }
    float res = (acc + hbuf[i * H + f] * isd) * isd + b1[f];
    h1[i * H + f] = fmaxf(res, 0.f);
}

// ---------------- k3: agg2 = (Â @ h1) @ W2 + b2, + cosine score
__global__ __launch_bounds__(256) void agg2_k(const float* __restrict__ h1,
                                              const float* __restrict__ W2,
                                              const float* __restrict__ b2,
                                              const float* __restrict__ aux,
                                              const int* __restrict__ cur,
                                              const int* __restrict__ csrc,
                                              float* __restrict__ h2,
                                              float* __restrict__ score) {
    __shared__ float w2s[64 * 64];
    __shared__ int2 sPair[NB * PAD];
    __shared__ int sDeg[NB];
    __shared__ float sIsd[NB];
    __shared__ float anorm[64];
    __shared__ float gsh[NB * 64];
    const int t = threadIdx.x, f = t & 63, w = t >> 6;
    const int base = blockIdx.x * NB;
    #pragma unroll
    for (int q = 0; q < 4; ++q) {
        int idx = t + q * 256;
        int r = idx >> 4, c4 = idx & 15;
        *(float4*)(&w2s[r * 64 + c4 * 4]) = *(const float4*)(W2 + r * H + c4 * 4);
    }
    if (t < NB) {
        int d = cur[(base + t) * CSTR];
        sDeg[t] = min(d, PAD);
        sIsd[t] = rsqrtf((float)d + 1.f);
    }
    if (t < 64) {
        float av = aux[t];
        anorm[t] = av * rsqrtf(fmaxf(wred_f(av * av), 1e-24f));
    }
    __syncthreads();
    for (int idx = t; idx < NB * PAD; idx += 256) {
        int n = idx / PAD, e = idx - n * PAD;
        if (e < sDeg[n]) {
            int s = csrc[(base + n) * PAD + e];
            float ws_ = rsqrtf((float)cur[s * CSTR] + 1.f);
            sPair[idx] = make_int2(s, __float_as_int(ws_));
        }
    }
    __syncthreads();
    const int i = base + w;
    const int deg = sDeg[w];
    const float isd = sIsd[w];
    const int2* pp = sPair + w * PAD;
    float acc = 0.f;
    int e = 0;
    for (; e + 4 <= deg; e += 4) {
        int2 p0 = pp[e], p1 = pp[e + 1], p2 = pp[e + 2], p3 = pp[e + 3];
        acc += h1[p0.x * H + f] * __int_as_float(p0.y)
             + h1[p1.x * H + f] * __int_as_float(p1.y)
             + h1[p2.x * H + f] * __int_as_float(p2.y)
             + h1[p3.x * H + f] * __int_as_float(p3.y);
    }
    for (; e < deg; ++e) {
        int2 p = pp[e];
        acc += h1[p.x * H + f] * __int_as_float(p.y);
    }
    float g = (acc + h1[i * H + f] * isd) * isd;
    gsh[w * 64 + f] = g;
    __builtin_amdgcn_wave_barrier();
    float hv = b2[f];
    #pragma unroll 16
    for (int k = 0; k < 64; ++k) hv += gsh[w * 64 + k] * w2s[k * 64 + f];
    h2[i * H + f] = hv;
    float dp = wred_f(hv * anorm[f]);
    float nn = wred_f(hv * hv);
    if (f == 0) score[i] = dp / fmaxf(sqrtf(nn), 1e-8f);
}

// ---------------- k4: moments M[k][f] = sum_j w_j s_j^k h2[j][f]; m0[k] likewise
__global__ __launch_bounds__(256) void momden_k(const float* __restrict__ h2,
                                                const float* __restrict__ score,
                                                double* __restrict__ M,
                                                double* __restrict__ m0) {
    const int t = threadIdx.x, f = t & 63, g = t >> 6;
    float accM[KTERMS], accD[KTERMS];
    #pragma unroll
    for (int k = 0; k < KTERMS; ++k) { accM[k] = 0.f; accD[k] = 0.f; }
    for (int j = blockIdx.x * 4 + g; j < N_NODES; j += MOM_BLKS * 4) {
        float sj = score[j];
        float wj = expf(-sj * sj);
        float hv = h2[j * H + f];
        float tm = wj * hv, td = wj;
        #pragma unroll
        for (int k = 0; k < KTERMS; ++k) {
            accM[k] += tm; tm *= sj;
            accD[k] += td; td *= sj;
        }
    }
    __shared__ float Msh[4 * KTERMS * 64];
    __shared__ float Dsh[4 * KTERMS];
    #pragma unroll
    for (int k = 0; k < KTERMS; ++k) Msh[(g * KTERMS + k) * 64 + f] = accM[k];
    if (f == 0) {
        #pragma unroll
        for (int k = 0; k < KTERMS; ++k) Dsh[g * KTERMS + k] = accD[k];
    }
    __syncthreads();
    for (int idx = t; idx < KTERMS * 64; idx += 256) {
        int k = idx >> 6, ff = idx & 63;
        float sum = Msh[(0 * KTERMS + k) * 64 + ff] + Msh[(1 * KTERMS + k) * 64 + ff]
                  + Msh[(2 * KTERMS + k) * 64 + ff] + Msh[(3 * KTERMS + k) * 64 + ff];
        unsafeAtomicAdd(&M[idx], (double)sum);
    }
    if (t < KTERMS) {
        float sum = Dsh[t] + Dsh[KTERMS + t] + Dsh[2 * KTERMS + t] + Dsh[3 * KTERMS + t];
        unsafeAtomicAdd(&m0[t], (double)sum);
    }
}

// ---------------- k5: z + concat classifier
__global__ __launch_bounds__(256) void final_k(const float* __restrict__ h2,
                                               const float* __restrict__ score,
                                               const double* __restrict__ M,
                                               const double* __restrict__ m0,
                                               const float* __restrict__ clfW,
                                               const float* __restrict__ clfb,
                                               float* __restrict__ out) {
    __shared__ float Ms[KTERMS * 64];
    __shared__ float m0s[KTERMS];
    __shared__ float cw[128 * C_CLS];
    __shared__ float cb[8];
    __shared__ float zh[4 * 128];
    const int t = threadIdx.x, f = t & 63, w = t >> 6;
    for (int idx = t; idx < KTERMS * 64; idx += 256) Ms[idx] = (float)M[idx];
    if (t < KTERMS) m0s[t] = (float)m0[t];
    for (int idx = t; idx < 128 * C_CLS; idx += 256) cw[idx] = clfW[idx];
    if (t < C_CLS) cb[t] = clfb[t];
    __syncthreads();
    const int base = blockIdx.x * 16;
    for (int q = 0; q < 4; ++q) {
        int i = base + q * 4 + w;
        float s = score[i];
        float c = expf(-s * s);
        float t2 = 2.f * s;
        float num = 0.f, den = 0.f;
        #pragma unroll
        for (int k = 0; k < KTERMS; ++k) {
            num += c * Ms[k * 64 + f];
            den += c * m0s[k];
            c *= t2 * (1.0f / (float)(k + 1));
        }
        zh[w * 128 + f] = h2[i * H + f];
        zh[w * 128 + 64 + f] = num / den;
        __builtin_amdgcn_wave_barrier();
        if (f < C_CLS) {
            float o = cb[f];
            #pragma unroll 8
            for (int u = 0; u < 128; ++u) o += zh[w * 128 + u] * cw[u * C_CLS + f];
            out[(size_t)i * C_CLS + f] = o;
        }
        __builtin_amdgcn_wave_barrier();
    }
}

// ---------------- launch
extern "C" void kernel_launch(void* const* d_in, const int* in_sizes, int n_in,
                              void* d_out, int out_size, void* d_ws, size_t ws_size,
                              hipStream_t stream) {
    (void)in_sizes; (void)n_in; (void)out_size; (void)ws_size;
    const float* x    = (const float*)d_in[0];
    const float* W1   = (const float*)d_in[1];
    const float* b1   = (const float*)d_in[2];
    const float* W2   = (const float*)d_in[3];
    const float* b2   = (const float*)d_in[4];
    const float* aux  = (const float*)d_in[5];
    const float* clfW = (const float*)d_in[6];
    const float* clfb = (const float*)d_in[7];
    const int*   ei   = (const int*)d_in[8];
    float* out = (float*)d_out;
    char* ws = (char*)d_ws;

    float*  hbuf  = (float*)(ws + 0);            // 3,072,000
    float*  h1    = (float*)(ws + 3072000);      // 3,072,000
    float*  h2    = (float*)(ws + 6144000);      // 3,072,000
    float*  score = (float*)(ws + 9216000);      // 48,000
    int*    csrc  = (int*)  (ws + 9264000);      // 4,608,000
    int*    cur   = (int*)  (ws + 13872000);     // 1,536,000 (padded lines)
    double* M     = (double*)(ws + 15408000);    // 8,192
    double* m0    = (double*)(ws + 15416192);    // 128

    init_k<<<47, 256, 0, stream>>>(cur, M, m0);
    k1_gemm_fill<<<1000, 256, 0, stream>>>(x, W1, ei, hbuf, cur, csrc);
    agg1_k<<<N_NODES / NB, 256, 0, stream>>>(hbuf, b1, cur, csrc, h1);
    agg2_k<<<N_NODES / NB, 256, 0, stream>>>(h1, W2, b2, aux, cur, csrc, h2, score);
    momden_k<<<MOM_BLKS, 256, 0, stream>>>(h2, score, M, m0);
    final_k<<<750, 256, 0, stream>>>(h2, score, M, m0, clfW, clfb, out);
}